// Round 5
// baseline (530.692 us; speedup 1.0000x reference)
//
#include <hip/hip_runtime.h>
#include <hip/hip_bf16.h>

#define NN 100000
#define NE 1000000
#define DIN 64
#define DH 128
#define NSCAN 98  // ceil(NN/1024)

// ---- workspace layout (32-bit words) ----
// hist[NN] | bnsum[128] | bnsq[128] | cA[128] | cC[128] | offs[NN+1] | pad |
// csr[NE] | plr[NN*4] | aggb[NN*64] | h[NN*128]
// xb (bf16, NN*64 = NN*32 words) overlays the FRONT of the h region:
//   lifetime xb = [k_cvt .. k_agg], lifetime h = [k_mm2 .. k_proj] -> disjoint.
#define OFF_HIST  0
#define OFF_BNSUM (NN)
#define OFF_BNSQ  (NN + 128)
#define OFF_CA    (NN + 256)
#define OFF_CC    (NN + 384)
#define OFF_OFFS  (NN + 512)
#define OFF_CSR   (OFF_OFFS + NN + 4)
#define OFF_PLR   (OFF_CSR + NE)
#define OFF_AGG   (OFF_PLR + NN * 4)
#define OFF_H     (OFF_AGG + NN * DIN)
#define WORDS_NEEDED ((size_t)OFF_H + (size_t)NN * DH)
// fallback (round-4) layout: h directly after plr
#define OFF_H_FB  (OFF_PLR + NN * 4)
#define WORDS_FB  ((size_t)OFF_H_FB + (size_t)NN * DH)

// ---------------- CSR build ----------------
__global__ __launch_bounds__(256) void k_hist(const int* __restrict__ dst, int* __restrict__ hist) {
    int e = blockIdx.x * 256 + threadIdx.x;
    if (e < NE) atomicAdd(&hist[dst[e]], 1);
}

__global__ __launch_bounds__(1024) void k_scan1(const int* __restrict__ hist,
                                                int* __restrict__ offs, int* __restrict__ bsum) {
    __shared__ int tmp[1024];
    int t = threadIdx.x, idx = blockIdx.x * 1024 + t;
    int v = (idx < NN) ? hist[idx] : 0;
    int sum = v;
    tmp[t] = sum;
    __syncthreads();
    for (int off = 1; off < 1024; off <<= 1) {
        int o = (t >= off) ? tmp[t - off] : 0;
        __syncthreads();
        sum += o;
        tmp[t] = sum;
        __syncthreads();
    }
    if (idx < NN) offs[idx] = sum - v;  // local exclusive
    if (t == 1023) bsum[blockIdx.x] = sum;
}

__global__ void k_scan2(int* __restrict__ bsum) {
    if (threadIdx.x == 0) {
        int acc = 0;
        for (int i = 0; i < NSCAN; ++i) { int v = bsum[i]; bsum[i] = acc; acc += v; }
    }
}

__global__ __launch_bounds__(1024) void k_scan3(int* __restrict__ offs, const int* __restrict__ bsum) {
    int t = threadIdx.x, idx = blockIdx.x * 1024 + t;
    if (idx < NN) offs[idx] += bsum[blockIdx.x];
    if (blockIdx.x == 0 && t == 0) offs[NN] = NE;
}

__global__ __launch_bounds__(256) void k_reorder(const int* __restrict__ src, const int* __restrict__ dst,
                                                 const int* __restrict__ offs, int* __restrict__ hist,
                                                 int* __restrict__ csr) {
    int e = blockIdx.x * 256 + threadIdx.x;
    if (e >= NE) return;
    int d = dst[e];
    int old = atomicSub(&hist[d], 1);  // count..1
    csr[offs[d] + old - 1] = src[e];
}

// ---------------- x -> bf16 ----------------
__global__ __launch_bounds__(256) void k_cvt(const float* __restrict__ x,
                                             __hip_bfloat16* __restrict__ xb) {
    int i = blockIdx.x * 256 + threadIdx.x;  // 8 elems each
    if (i >= NN * DIN / 8) return;
    float4 a = *(const float4*)(x + (size_t)i * 8);
    float4 b = *(const float4*)(x + (size_t)i * 8 + 4);
    __hip_bfloat16 o[8];
    o[0] = __float2bfloat16(a.x); o[1] = __float2bfloat16(a.y);
    o[2] = __float2bfloat16(a.z); o[3] = __float2bfloat16(a.w);
    o[4] = __float2bfloat16(b.x); o[5] = __float2bfloat16(b.y);
    o[6] = __float2bfloat16(b.z); o[7] = __float2bfloat16(b.w);
    *(uint4*)&xb[(size_t)i * 8] = *(uint4*)o;
}

// ---------------- agg (primary): CSR gather-mean over bf16 x rows ----------------
__global__ __launch_bounds__(256) void k_agg_bf16(const __hip_bfloat16* __restrict__ xb,
                                                  const int* __restrict__ offs,
                                                  const int* __restrict__ csr,
                                                  float* __restrict__ aggb) {
    int wid = (blockIdx.x * 256 + threadIdx.x) >> 6;  // node
    int lane = threadIdx.x & 63;
    if (wid >= NN) return;
    int beg = offs[wid];
    int deg = offs[wid + 1] - beg;
    float acc = 0.f;
    for (int ch = 0; ch < deg; ch += 64) {
        int m = min(deg - ch, 64);
        int sv = (lane < m) ? csr[beg + ch + lane] : 0;
        int j = 0;
        for (; j + 8 <= m; j += 8) {
            float a0 = __bfloat162float(xb[(size_t)__shfl(sv, j + 0) * DIN + lane]);
            float a1 = __bfloat162float(xb[(size_t)__shfl(sv, j + 1) * DIN + lane]);
            float a2 = __bfloat162float(xb[(size_t)__shfl(sv, j + 2) * DIN + lane]);
            float a3 = __bfloat162float(xb[(size_t)__shfl(sv, j + 3) * DIN + lane]);
            float a4 = __bfloat162float(xb[(size_t)__shfl(sv, j + 4) * DIN + lane]);
            float a5 = __bfloat162float(xb[(size_t)__shfl(sv, j + 5) * DIN + lane]);
            float a6 = __bfloat162float(xb[(size_t)__shfl(sv, j + 6) * DIN + lane]);
            float a7 = __bfloat162float(xb[(size_t)__shfl(sv, j + 7) * DIN + lane]);
            acc += ((a0 + a1) + (a2 + a3)) + ((a4 + a5) + (a6 + a7));
        }
        for (; j < m; ++j)
            acc += __bfloat162float(xb[(size_t)__shfl(sv, j) * DIN + lane]);
    }
    aggb[(size_t)wid * DIN + lane] = acc / fmaxf((float)deg, 1.f);
}

// ---------------- GEMM (primary): scalar-operand dual matmul, no LDS in main loop ----------------
// 256 thr = 4 waves. wave w: channels c = (w&1)*64+lane, node-half = w>>1 (16 nodes of 32-tile).
// Node indices derived via readfirstlane -> aggb/x loads are wave-uniform scalar loads;
// inner loop is v_fmac acc, s_a, v_w with 8 independent chains.
__global__ __launch_bounds__(256) void k_mm2(const float* __restrict__ x,
                                             const float* __restrict__ aggb,
                                             const float* __restrict__ W1l,
                                             const float* __restrict__ W1r,
                                             const float* __restrict__ b1,
                                             float* __restrict__ h,
                                             float* __restrict__ bnsum,
                                             float* __restrict__ bnsq) {
    const int lane = threadIdx.x & 63;
    const int w = threadIdx.x >> 6;
    const int c = ((w & 1) << 6) | lane;

    float wl[DIN], wr[DIN];
#pragma unroll
    for (int k = 0; k < DIN; ++k) {
        wl[k] = W1l[k * DH + c];
        wr[k] = W1r[k * DH + c];
    }
    const float bias = b1[c];

    float psum = 0.f, psq = 0.f;

    for (int base = blockIdx.x * 32; base < NN; base += gridDim.x * 32) {
        const int nb = __builtin_amdgcn_readfirstlane(base + (w >> 1) * 16);
#pragma unroll
        for (int g = 0; g < 4; ++g) {
            const int n0 = nb + g * 4;
            const float* a0 = aggb + (size_t)(n0 + 0) * DIN;
            const float* a1 = aggb + (size_t)(n0 + 1) * DIN;
            const float* a2 = aggb + (size_t)(n0 + 2) * DIN;
            const float* a3 = aggb + (size_t)(n0 + 3) * DIN;
            const float* x0 = x + (size_t)(n0 + 0) * DIN;
            const float* x1 = x + (size_t)(n0 + 1) * DIN;
            const float* x2 = x + (size_t)(n0 + 2) * DIN;
            const float* x3 = x + (size_t)(n0 + 3) * DIN;
            float sA0 = 0.f, sA1 = 0.f, sA2 = 0.f, sA3 = 0.f;
            float sX0 = 0.f, sX1 = 0.f, sX2 = 0.f, sX3 = 0.f;
#pragma unroll
            for (int k = 0; k < DIN; ++k) {
                sA0 += a0[k] * wl[k];
                sA1 += a1[k] * wl[k];
                sA2 += a2[k] * wl[k];
                sA3 += a3[k] * wl[k];
                sX0 += x0[k] * wr[k];
                sX1 += x1[k] * wr[k];
                sX2 += x2[k] * wr[k];
                sX3 += x3[k] * wr[k];
            }
            float o0 = bias + sA0 + sX0;
            float o1 = bias + sA1 + sX1;
            float o2 = bias + sA2 + sX2;
            float o3 = bias + sA3 + sX3;
            h[(size_t)(n0 + 0) * DH + c] = o0;
            h[(size_t)(n0 + 1) * DH + c] = o1;
            h[(size_t)(n0 + 2) * DH + c] = o2;
            h[(size_t)(n0 + 3) * DH + c] = o3;
            psum += (o0 + o1) + (o2 + o3);
            psq += (o0 * o0 + o1 * o1) + (o2 * o2 + o3 * o3);
        }
    }

    // BN partial reduce: threads t and t+128 share channel c==t (t<128)
    __shared__ float red[512];
    red[threadIdx.x] = psum;
    red[256 + threadIdx.x] = psq;
    __syncthreads();
    int t = threadIdx.x;
    if (t < 128) {
        atomicAdd(&bnsum[t], red[t] + red[t + 128]);
        atomicAdd(&bnsq[t], red[256 + t] + red[256 + t + 128]);
    }
}

// ---------------- fallback (round-4) agg + LDS GEMM ----------------
__global__ __launch_bounds__(256) void k_agg32(const float* __restrict__ x,
                                               const int* __restrict__ offs,
                                               const int* __restrict__ csr,
                                               float* __restrict__ h) {
    int wid = (blockIdx.x * 256 + threadIdx.x) >> 6;
    int lane = threadIdx.x & 63;
    if (wid >= NN) return;
    int beg = offs[wid];
    int deg = offs[wid + 1] - beg;
    float acc = 0.f;
    for (int ch = 0; ch < deg; ch += 64) {
        int m = min(deg - ch, 64);
        int sv = (lane < m) ? csr[beg + ch + lane] : 0;
        for (int j = 0; j < m; ++j)
            acc += x[(size_t)__shfl(sv, j) * DIN + lane];
    }
    h[(size_t)wid * DH + lane] = acc / fmaxf((float)deg, 1.f);
}

__global__ __launch_bounds__(256, 2) void k_mm_lds(const float* __restrict__ x,
                                                   const float* __restrict__ W1l,
                                                   const float* __restrict__ W1r,
                                                   const float* __restrict__ b1,
                                                   float* h,
                                                   float* __restrict__ bnsum,
                                                   float* __restrict__ bnsq) {
    const int c = threadIdx.x & 127;
    const int sub = threadIdx.x >> 7;
    float wl[DIN], wr[DIN];
#pragma unroll
    for (int k = 0; k < DIN; ++k) {
        wl[k] = W1l[k * DH + c];
        wr[k] = W1r[k * DH + c];
    }
    const float bias = b1[c];
    __shared__ __align__(16) float sA[32][DIN];
    __shared__ __align__(16) float sX[32][DIN];
    float psum = 0.f, psq = 0.f;
    for (int base = blockIdx.x * 32; base < NN; base += gridDim.x * 32) {
        __syncthreads();
#pragma unroll
        for (int i = 0; i < 2; ++i) {
            int f = threadIdx.x + i * 256;
            int row = f >> 4, col = (f & 15) * 4;
            *(float4*)&sA[row][col] = *(const float4*)&h[(size_t)(base + row) * DH + col];
            *(float4*)&sX[row][col] = *(const float4*)&x[(size_t)(base + row) * DIN + col];
        }
        __syncthreads();
        const int nb = sub * 16;
#pragma unroll
        for (int n = 0; n < 16; ++n) {
            float acc = bias;
#pragma unroll
            for (int kk = 0; kk < DIN; kk += 4) {
                float4 a4 = *(const float4*)&sA[nb + n][kk];
                float4 x4 = *(const float4*)&sX[nb + n][kk];
                acc += a4.x * wl[kk] + a4.y * wl[kk + 1] + a4.z * wl[kk + 2] + a4.w * wl[kk + 3];
                acc += x4.x * wr[kk] + x4.y * wr[kk + 1] + x4.z * wr[kk + 2] + x4.w * wr[kk + 3];
            }
            h[(size_t)(base + nb + n) * DH + c] = acc;
            psum += acc;
            psq += acc * acc;
        }
    }
    float* rr = &sA[0][0];
    __syncthreads();
    if (sub == 1) { rr[c] = psum; rr[128 + c] = psq; }
    __syncthreads();
    if (sub == 0) {
        atomicAdd(&bnsum[c], psum + rr[c]);
        atomicAdd(&bnsq[c], psq + rr[128 + c]);
    }
}

// ---------------- fold BN into per-channel affine ----------------
__global__ void k_bnfin(const float* __restrict__ bnsum, const float* __restrict__ bnsq,
                        const float* __restrict__ gamma, const float* __restrict__ beta,
                        float* __restrict__ cA, float* __restrict__ cC) {
    int c = threadIdx.x;
    if (c < DH) {
        float mu = bnsum[c] * (1.f / NN);
        float var = bnsq[c] * (1.f / NN) - mu * mu;
        float a = rsqrtf(var + 1e-5f) * gamma[c];
        cA[c] = a;
        cC[c] = beta[c] - mu * a;
    }
}

// ---------------- per-node projection: plr[n] = {hb@W2l (2), hb@W2r (2)} ----------------
__global__ __launch_bounds__(256) void k_proj(const float* __restrict__ h,
                                              const float* __restrict__ cA,
                                              const float* __restrict__ cC,
                                              const float* __restrict__ W2l,
                                              const float* __restrict__ W2r,
                                              float4* __restrict__ plr) {
    int wid = (blockIdx.x * 256 + threadIdx.x) >> 6;  // node
    int lane = threadIdx.x & 63;
    if (wid >= NN) return;
    int c0 = lane * 2;
    float2 hv = *(const float2*)&h[(size_t)wid * DH + c0];
    float hb0 = fmaxf(hv.x * cA[c0] + cC[c0], 0.f);
    float hb1 = fmaxf(hv.y * cA[c0 + 1] + cC[c0 + 1], 0.f);
    float pl0 = hb0 * W2l[c0 * 2 + 0] + hb1 * W2l[c0 * 2 + 2];
    float pl1 = hb0 * W2l[c0 * 2 + 1] + hb1 * W2l[c0 * 2 + 3];
    float pr0 = hb0 * W2r[c0 * 2 + 0] + hb1 * W2r[c0 * 2 + 2];
    float pr1 = hb0 * W2r[c0 * 2 + 1] + hb1 * W2r[c0 * 2 + 3];
#pragma unroll
    for (int off = 32; off > 0; off >>= 1) {
        pl0 += __shfl_down(pl0, off);
        pl1 += __shfl_down(pl1, off);
        pr0 += __shfl_down(pr0, off);
        pr1 += __shfl_down(pr1, off);
    }
    if (lane == 0) plr[wid] = make_float4(pl0, pl1, pr0, pr1);
}

// ---------------- layer-2 aggregate + output ----------------
__global__ __launch_bounds__(256) void k_out(const float4* __restrict__ plr,
                                             const int* __restrict__ offs,
                                             const int* __restrict__ csr,
                                             const float* __restrict__ b2,
                                             float* __restrict__ out) {
    int d = blockIdx.x * 256 + threadIdx.x;
    if (d >= NN) return;
    int beg = offs[d];
    int deg = offs[d + 1] - beg;
    const float2* pl2 = (const float2*)plr;
    float s0 = 0.f, s1 = 0.f;
    for (int i = 0; i < deg; ++i) {
        int s = csr[beg + i];
        float2 p = pl2[(size_t)s * 2];
        s0 += p.x;
        s1 += p.y;
    }
    float inv = 1.f / fmaxf((float)deg, 1.f);
    float4 me = plr[d];
    out[(size_t)d * 2 + 0] = s0 * inv + me.z + b2[0];
    out[(size_t)d * 2 + 1] = s1 * inv + me.w + b2[1];
}

extern "C" void kernel_launch(void* const* d_in, const int* in_sizes, int n_in,
                              void* d_out, int out_size, void* d_ws, size_t ws_size,
                              hipStream_t stream) {
    const float* x = (const float*)d_in[0];
    const int* ei = (const int*)d_in[1];
    const float* W1l = (const float*)d_in[2];
    const float* W1r = (const float*)d_in[3];
    const float* b1 = (const float*)d_in[4];
    const float* gamma = (const float*)d_in[5];
    const float* beta = (const float*)d_in[6];
    const float* W2l = (const float*)d_in[7];
    const float* W2r = (const float*)d_in[8];
    const float* b2 = (const float*)d_in[9];
    float* out = (float*)d_out;
    float* ws = (float*)d_ws;
    int* wsi = (int*)d_ws;

    const int* src = ei;
    const int* dst = ei + NE;

    int* hist = wsi + OFF_HIST;
    int* offs = wsi + OFF_OFFS;
    int* csr = wsi + OFF_CSR;
    int* bsum = wsi + OFF_PLR;  // scan partials borrow plr front (dead until k_proj)
    float* bnsum = ws + OFF_BNSUM;
    float* bnsq = ws + OFF_BNSQ;
    float* cA = ws + OFF_CA;
    float* cC = ws + OFF_CC;
    float4* plr = (float4*)(ws + OFF_PLR);

    const bool big = ws_size >= WORDS_NEEDED * sizeof(float);
    float* h = big ? (ws + OFF_H) : (ws + OFF_H_FB);
    float* aggb = ws + OFF_AGG;                       // primary only
    __hip_bfloat16* xb = (__hip_bfloat16*)h;          // overlays h front; dead before k_mm2

    // zero hist + bn partials
    hipMemsetAsync(ws, 0, (size_t)(NN + 256) * sizeof(float), stream);

    k_hist<<<(NE + 255) / 256, 256, 0, stream>>>(dst, hist);
    k_scan1<<<NSCAN, 1024, 0, stream>>>(hist, offs, bsum);
    k_scan2<<<1, 64, 0, stream>>>(bsum);
    k_scan3<<<NSCAN, 1024, 0, stream>>>(offs, bsum);
    k_reorder<<<(NE + 255) / 256, 256, 0, stream>>>(src, dst, offs, hist, csr);

    if (big) {
        k_cvt<<<(NN * DIN / 8 + 255) / 256, 256, 0, stream>>>(x, xb);
        k_agg_bf16<<<(NN * 64 + 255) / 256, 256, 0, stream>>>(xb, offs, csr, aggb);
        k_mm2<<<1024, 256, 0, stream>>>(x, aggb, W1l, W1r, b1, h, bnsum, bnsq);
    } else {
        k_agg32<<<(NN * 64 + 255) / 256, 256, 0, stream>>>(x, offs, csr, h);
        k_mm_lds<<<1024, 256, 0, stream>>>(x, W1l, W1r, b1, h, bnsum, bnsq);
    }

    k_bnfin<<<1, 128, 0, stream>>>(bnsum, bnsq, gamma, beta, cA, cC);
    k_proj<<<(NN + 3) / 4, 256, 0, stream>>>(h, cA, cC, W2l, W2r, plr);
    k_out<<<(NN + 255) / 256, 256, 0, stream>>>(plr, offs, csr, b2, out);
}

// Round 7
// 348.094 us; speedup vs baseline: 1.5246x; 1.5246x over previous
//
#include <hip/hip_runtime.h>
#include <hip/hip_bf16.h>

#define NN 100000
#define NE 1000000
#define DIN 64
#define DH 128
#define NSCAN 98  // ceil(NN/1024)

typedef __attribute__((ext_vector_type(8))) short short8;
typedef __attribute__((ext_vector_type(4))) float floatx4;

// ---- workspace layout (32-bit words) ----
// hist[NN] | bnsum[128] | bnsq[128] | cA[128] | cC[128] | offs[NN+1]+pad |
// csr[NE] | plr[NN*4] | wfrag[8192] | aggb16[NN*32] | xb[NN*32] | h[NN*128]
#define OFF_HIST  0
#define OFF_BNSUM (NN)
#define OFF_BNSQ  (NN + 128)
#define OFF_CA    (NN + 256)
#define OFF_CC    (NN + 384)
#define OFF_OFFS  (NN + 512)
#define OFF_CSR   (OFF_OFFS + NN + 4)
#define OFF_PLR   (OFF_CSR + NE)
#define OFF_WF    (OFF_PLR + NN * 4)
#define OFF_AGB   (OFF_WF + 8192)
#define OFF_XB    (OFF_AGB + NN * 32)
#define OFF_H     (OFF_XB + NN * 32)
#define WORDS_NEEDED ((size_t)OFF_H + (size_t)NN * DH)
// fallback (round-4) layout: h directly after plr
#define OFF_H_FB  (OFF_PLR + NN * 4)

// ---------------- CSR build ----------------
__global__ __launch_bounds__(256) void k_hist(const int* __restrict__ dst, int* __restrict__ hist) {
    int e = blockIdx.x * 256 + threadIdx.x;
    if (e < NE) atomicAdd(&hist[dst[e]], 1);
}

__global__ __launch_bounds__(1024) void k_scan1(const int* __restrict__ hist,
                                                int* __restrict__ offs, int* __restrict__ bsum) {
    __shared__ int tmp[1024];
    int t = threadIdx.x, idx = blockIdx.x * 1024 + t;
    int v = (idx < NN) ? hist[idx] : 0;
    int sum = v;
    tmp[t] = sum;
    __syncthreads();
    for (int off = 1; off < 1024; off <<= 1) {
        int o = (t >= off) ? tmp[t - off] : 0;
        __syncthreads();
        sum += o;
        tmp[t] = sum;
        __syncthreads();
    }
    if (idx < NN) offs[idx] = sum - v;  // local exclusive
    if (t == 1023) bsum[blockIdx.x] = sum;
}

__global__ void k_scan2(int* __restrict__ bsum) {
    if (threadIdx.x == 0) {
        int acc = 0;
        for (int i = 0; i < NSCAN; ++i) { int v = bsum[i]; bsum[i] = acc; acc += v; }
    }
}

__global__ __launch_bounds__(1024) void k_scan3(int* __restrict__ offs, const int* __restrict__ bsum) {
    int t = threadIdx.x, idx = blockIdx.x * 1024 + t;
    if (idx < NN) offs[idx] += bsum[blockIdx.x];
    if (blockIdx.x == 0 && t == 0) offs[NN] = NE;
}

__global__ __launch_bounds__(256) void k_reorder(const int* __restrict__ src, const int* __restrict__ dst,
                                                 const int* __restrict__ offs, int* __restrict__ hist,
                                                 int* __restrict__ csr) {
    int e = blockIdx.x * 256 + threadIdx.x;
    if (e >= NE) return;
    int d = dst[e];
    int old = atomicSub(&hist[d], 1);  // count..1
    csr[offs[d] + old - 1] = src[e];
}

// ---------------- x -> bf16 ----------------
__global__ __launch_bounds__(256) void k_cvt(const float* __restrict__ x,
                                             ushort* __restrict__ xb) {
    int i = blockIdx.x * 256 + threadIdx.x;  // 8 elems each
    if (i >= NN * DIN / 8) return;
    float4 a = *(const float4*)(x + (size_t)i * 8);
    float4 b = *(const float4*)(x + (size_t)i * 8 + 4);
    __hip_bfloat16 o[8];
    o[0] = __float2bfloat16(a.x); o[1] = __float2bfloat16(a.y);
    o[2] = __float2bfloat16(a.z); o[3] = __float2bfloat16(a.w);
    o[4] = __float2bfloat16(b.x); o[5] = __float2bfloat16(b.y);
    o[6] = __float2bfloat16(b.z); o[7] = __float2bfloat16(b.w);
    *(uint4*)&xb[(size_t)i * 8] = *(uint4*)o;
}

// ---------------- weights -> bf16 MFMA B-fragment order ----------------
// wfrag[((ct*4+ks)*64 + lane)*8 + j] = Wcat[ks*32 + (lane>>4)*8 + j][ct*16 + (lane&15)]
// where Wcat rows 0..63 = W1l, 64..127 = W1r.
__global__ __launch_bounds__(256) void k_cvtw(const float* __restrict__ W1l,
                                              const float* __restrict__ W1r,
                                              ushort* __restrict__ wfrag) {
    int t = blockIdx.x * 256 + threadIdx.x;  // 0..2047
    if (t >= 2048) return;
    int ct = t >> 8, ks = (t >> 6) & 3, l = t & 63;
    int k0 = ks * 32 + (l >> 4) * 8;
    int col = ct * 16 + (l & 15);
    ushort o[8];
#pragma unroll
    for (int j = 0; j < 8; ++j) {
        int k = k0 + j;
        float v = (k < 64) ? W1l[k * DH + col] : W1r[(k - 64) * DH + col];
        __hip_bfloat16 b = __float2bfloat16(v);
        o[j] = *(ushort*)&b;
    }
    *(uint4*)&wfrag[(size_t)t * 8] = *(uint4*)o;
}

// ---------------- agg: CSR gather-mean over bf16 x rows, bf16 out ----------------
__global__ __launch_bounds__(256) void k_agg_bf16(const __hip_bfloat16* __restrict__ xb,
                                                  const int* __restrict__ offs,
                                                  const int* __restrict__ csr,
                                                  ushort* __restrict__ aggb16) {
    int wid = (blockIdx.x * 256 + threadIdx.x) >> 6;  // node
    int lane = threadIdx.x & 63;
    if (wid >= NN) return;
    int beg = offs[wid];
    int deg = offs[wid + 1] - beg;
    float acc = 0.f;
    for (int ch = 0; ch < deg; ch += 64) {
        int m = min(deg - ch, 64);
        int sv = (lane < m) ? csr[beg + ch + lane] : 0;
        int j = 0;
        for (; j + 8 <= m; j += 8) {
            float a0 = __bfloat162float(xb[(size_t)__shfl(sv, j + 0) * DIN + lane]);
            float a1 = __bfloat162float(xb[(size_t)__shfl(sv, j + 1) * DIN + lane]);
            float a2 = __bfloat162float(xb[(size_t)__shfl(sv, j + 2) * DIN + lane]);
            float a3 = __bfloat162float(xb[(size_t)__shfl(sv, j + 3) * DIN + lane]);
            float a4 = __bfloat162float(xb[(size_t)__shfl(sv, j + 4) * DIN + lane]);
            float a5 = __bfloat162float(xb[(size_t)__shfl(sv, j + 5) * DIN + lane]);
            float a6 = __bfloat162float(xb[(size_t)__shfl(sv, j + 6) * DIN + lane]);
            float a7 = __bfloat162float(xb[(size_t)__shfl(sv, j + 7) * DIN + lane]);
            acc += ((a0 + a1) + (a2 + a3)) + ((a4 + a5) + (a6 + a7));
        }
        for (; j < m; ++j)
            acc += __bfloat162float(xb[(size_t)__shfl(sv, j) * DIN + lane]);
    }
    __hip_bfloat16 bv = __float2bfloat16(acc / fmaxf((float)deg, 1.f));
    aggb16[(size_t)wid * DIN + lane] = *(ushort*)&bv;
}

// ---------------- MFMA dual-GEMM: h = [agg|x] @ [W1l;W1r] + b1, BN partials ----------------
// 4 waves; wave w computes the 16-node stripe [tb+16w, tb+16w+16) x all 128 channels.
// A-frag (16x16x32 bf16): row=lane%16, k=(lane/16)*8+j.  B-frag: col=lane%16, same k.
// D: col=lane&15, row=(lane>>4)*4+reg (m89-verified).
__global__ __launch_bounds__(256, 2) void k_mmx(const ushort* __restrict__ aggb16,
                                                const ushort* __restrict__ xb,
                                                const ushort* __restrict__ wfrag,
                                                const float* __restrict__ b1,
                                                float* __restrict__ h,
                                                float* __restrict__ bnsum,
                                                float* __restrict__ bnsq) {
    __shared__ ushort sW[16384];     // 32 KB: B-fragments
    __shared__ ushort sA[64 * 136];  // 17 KB: A tile, padded stride 136 (bank-spread)
    const int tid = threadIdx.x;
    const int l = tid & 63, w = tid >> 6;
    const int r0 = l & 15, kg = l >> 4;

    {  // stage weight fragments once
        const uint4* wsrc = (const uint4*)wfrag;
        uint4* wdst = (uint4*)sW;
#pragma unroll
        for (int i = 0; i < 8; ++i) wdst[tid + i * 256] = wsrc[tid + i * 256];
    }

    float bias8[8];
#pragma unroll
    for (int ct = 0; ct < 8; ++ct) bias8[ct] = b1[ct * 16 + r0];

    float psum8[8] = {0, 0, 0, 0, 0, 0, 0, 0};
    float psq8[8] = {0, 0, 0, 0, 0, 0, 0, 0};

    __syncthreads();

    const int ntiles = (NN + 63) / 64;
    for (int tile = blockIdx.x; tile < ntiles; tile += gridDim.x) {
        const int tb = tile * 64;
        // stage A: 64 rows x (64 agg | 64 x) bf16
#pragma unroll
        for (int i = 0; i < 4; ++i) {
            int f = tid + i * 256;  // 0..1023 16B-chunks
            int row = f >> 4, ch = f & 15;
            const uint4* src = (ch < 8)
                ? (const uint4*)(aggb16 + (size_t)(tb + row) * 64 + ch * 8)
                : (const uint4*)(xb + (size_t)(tb + row) * 64 + (ch - 8) * 8);
            *(uint4*)&sA[row * 136 + ch * 8] = *src;
        }
        __syncthreads();

        short8 af[4];
        const int abase = (w * 16 + r0) * 136 + kg * 8;
#pragma unroll
        for (int ks = 0; ks < 4; ++ks)
            af[ks] = *(const short8*)&sA[abase + ks * 32];

#pragma unroll
        for (int ct = 0; ct < 8; ++ct) {
            floatx4 acc = {0.f, 0.f, 0.f, 0.f};
#pragma unroll
            for (int ks = 0; ks < 4; ++ks) {
                short8 bf = *(const short8*)&sW[((ct * 4 + ks) * 64 + l) * 8];
                acc = __builtin_amdgcn_mfma_f32_16x16x32_bf16(af[ks], bf, acc, 0, 0, 0);
            }
            const int col = ct * 16 + r0;
#pragma unroll
            for (int i = 0; i < 4; ++i) {
                int r = tb + w * 16 + kg * 4 + i;
                if (r < NN) {
                    float o = acc[i] + bias8[ct];
                    h[(size_t)r * DH + col] = o;
                    psum8[ct] += o;
                    psq8[ct] += o * o;
                }
            }
        }
        __syncthreads();
    }

#pragma unroll
    for (int ct = 0; ct < 8; ++ct) {
        float s = psum8[ct], q = psq8[ct];
        s += __shfl_xor(s, 16); s += __shfl_xor(s, 32);
        q += __shfl_xor(q, 16); q += __shfl_xor(q, 32);
        if (l < 16) {
            atomicAdd(&bnsum[ct * 16 + l], s);
            atomicAdd(&bnsq[ct * 16 + l], q);
        }
    }
}

// ---------------- fallback (round-4) agg + LDS GEMM ----------------
__global__ __launch_bounds__(256) void k_agg32(const float* __restrict__ x,
                                               const int* __restrict__ offs,
                                               const int* __restrict__ csr,
                                               float* __restrict__ h) {
    int wid = (blockIdx.x * 256 + threadIdx.x) >> 6;
    int lane = threadIdx.x & 63;
    if (wid >= NN) return;
    int beg = offs[wid];
    int deg = offs[wid + 1] - beg;
    float acc = 0.f;
    for (int ch = 0; ch < deg; ch += 64) {
        int m = min(deg - ch, 64);
        int sv = (lane < m) ? csr[beg + ch + lane] : 0;
        for (int j = 0; j < m; ++j)
            acc += x[(size_t)__shfl(sv, j) * DIN + lane];
    }
    h[(size_t)wid * DH + lane] = acc / fmaxf((float)deg, 1.f);
}

__global__ __launch_bounds__(256, 2) void k_mm_lds(const float* __restrict__ x,
                                                   const float* __restrict__ W1l,
                                                   const float* __restrict__ W1r,
                                                   const float* __restrict__ b1,
                                                   float* h,
                                                   float* __restrict__ bnsum,
                                                   float* __restrict__ bnsq) {
    const int c = threadIdx.x & 127;
    const int sub = threadIdx.x >> 7;
    float wl[DIN], wr[DIN];
#pragma unroll
    for (int k = 0; k < DIN; ++k) {
        wl[k] = W1l[k * DH + c];
        wr[k] = W1r[k * DH + c];
    }
    const float bias = b1[c];
    __shared__ __align__(16) float sA[32][DIN];
    __shared__ __align__(16) float sX[32][DIN];
    float psum = 0.f, psq = 0.f;
    for (int base = blockIdx.x * 32; base < NN; base += gridDim.x * 32) {
        __syncthreads();
#pragma unroll
        for (int i = 0; i < 2; ++i) {
            int f = threadIdx.x + i * 256;
            int row = f >> 4, col = (f & 15) * 4;
            *(float4*)&sA[row][col] = *(const float4*)&h[(size_t)(base + row) * DH + col];
            *(float4*)&sX[row][col] = *(const float4*)&x[(size_t)(base + row) * DIN + col];
        }
        __syncthreads();
        const int nb = sub * 16;
#pragma unroll
        for (int n = 0; n < 16; ++n) {
            float acc = bias;
#pragma unroll
            for (int kk = 0; kk < DIN; kk += 4) {
                float4 a4 = *(const float4*)&sA[nb + n][kk];
                float4 x4 = *(const float4*)&sX[nb + n][kk];
                acc += a4.x * wl[kk] + a4.y * wl[kk + 1] + a4.z * wl[kk + 2] + a4.w * wl[kk + 3];
                acc += x4.x * wr[kk] + x4.y * wr[kk + 1] + x4.z * wr[kk + 2] + x4.w * wr[kk + 3];
            }
            h[(size_t)(base + nb + n) * DH + c] = acc;
            psum += acc;
            psq += acc * acc;
        }
    }
    float* rr = &sA[0][0];
    __syncthreads();
    if (sub == 1) { rr[c] = psum; rr[128 + c] = psq; }
    __syncthreads();
    if (sub == 0) {
        atomicAdd(&bnsum[c], psum + rr[c]);
        atomicAdd(&bnsq[c], psq + rr[128 + c]);
    }
}

// ---------------- fold BN into per-channel affine ----------------
__global__ void k_bnfin(const float* __restrict__ bnsum, const float* __restrict__ bnsq,
                        const float* __restrict__ gamma, const float* __restrict__ beta,
                        float* __restrict__ cA, float* __restrict__ cC) {
    int c = threadIdx.x;
    if (c < DH) {
        float mu = bnsum[c] * (1.f / NN);
        float var = bnsq[c] * (1.f / NN) - mu * mu;
        float a = rsqrtf(var + 1e-5f) * gamma[c];
        cA[c] = a;
        cC[c] = beta[c] - mu * a;
    }
}

// ---------------- per-node projection: plr[n] = {hb@W2l (2), hb@W2r (2)} ----------------
__global__ __launch_bounds__(256) void k_proj(const float* __restrict__ h,
                                              const float* __restrict__ cA,
                                              const float* __restrict__ cC,
                                              const float* __restrict__ W2l,
                                              const float* __restrict__ W2r,
                                              float4* __restrict__ plr) {
    int wid = (blockIdx.x * 256 + threadIdx.x) >> 6;  // node
    int lane = threadIdx.x & 63;
    if (wid >= NN) return;
    int c0 = lane * 2;
    float2 hv = *(const float2*)&h[(size_t)wid * DH + c0];
    float hb0 = fmaxf(hv.x * cA[c0] + cC[c0], 0.f);
    float hb1 = fmaxf(hv.y * cA[c0 + 1] + cC[c0 + 1], 0.f);
    float pl0 = hb0 * W2l[c0 * 2 + 0] + hb1 * W2l[c0 * 2 + 2];
    float pl1 = hb0 * W2l[c0 * 2 + 1] + hb1 * W2l[c0 * 2 + 3];
    float pr0 = hb0 * W2r[c0 * 2 + 0] + hb1 * W2r[c0 * 2 + 2];
    float pr1 = hb0 * W2r[c0 * 2 + 1] + hb1 * W2r[c0 * 2 + 3];
#pragma unroll
    for (int off = 32; off > 0; off >>= 1) {
        pl0 += __shfl_down(pl0, off);
        pl1 += __shfl_down(pl1, off);
        pr0 += __shfl_down(pr0, off);
        pr1 += __shfl_down(pr1, off);
    }
    if (lane == 0) plr[wid] = make_float4(pl0, pl1, pr0, pr1);
}

// ---------------- layer-2 aggregate + output ----------------
__global__ __launch_bounds__(256) void k_out(const float4* __restrict__ plr,
                                             const int* __restrict__ offs,
                                             const int* __restrict__ csr,
                                             const float* __restrict__ b2,
                                             float* __restrict__ out) {
    int d = blockIdx.x * 256 + threadIdx.x;
    if (d >= NN) return;
    int beg = offs[d];
    int deg = offs[d + 1] - beg;
    const float2* pl2 = (const float2*)plr;
    float s0 = 0.f, s1 = 0.f;
    for (int i = 0; i < deg; ++i) {
        int s = csr[beg + i];
        float2 p = pl2[(size_t)s * 2];
        s0 += p.x;
        s1 += p.y;
    }
    float inv = 1.f / fmaxf((float)deg, 1.f);
    float4 me = plr[d];
    out[(size_t)d * 2 + 0] = s0 * inv + me.z + b2[0];
    out[(size_t)d * 2 + 1] = s1 * inv + me.w + b2[1];
}

extern "C" void kernel_launch(void* const* d_in, const int* in_sizes, int n_in,
                              void* d_out, int out_size, void* d_ws, size_t ws_size,
                              hipStream_t stream) {
    const float* x = (const float*)d_in[0];
    const int* ei = (const int*)d_in[1];
    const float* W1l = (const float*)d_in[2];
    const float* W1r = (const float*)d_in[3];
    const float* b1 = (const float*)d_in[4];
    const float* gamma = (const float*)d_in[5];
    const float* beta = (const float*)d_in[6];
    const float* W2l = (const float*)d_in[7];
    const float* W2r = (const float*)d_in[8];
    const float* b2 = (const float*)d_in[9];
    float* out = (float*)d_out;
    float* ws = (float*)d_ws;
    int* wsi = (int*)d_ws;

    const int* src = ei;
    const int* dst = ei + NE;

    int* hist = wsi + OFF_HIST;
    int* offs = wsi + OFF_OFFS;
    int* csr = wsi + OFF_CSR;
    int* bsum = wsi + OFF_PLR;  // scan partials borrow plr front (dead until k_proj)
    float* bnsum = ws + OFF_BNSUM;
    float* bnsq = ws + OFF_BNSQ;
    float* cA = ws + OFF_CA;
    float* cC = ws + OFF_CC;
    float4* plr = (float4*)(ws + OFF_PLR);

    const bool big = ws_size >= WORDS_NEEDED * sizeof(float);
    float* h = big ? (ws + OFF_H) : (ws + OFF_H_FB);
    ushort* wfrag = (ushort*)(ws + OFF_WF);
    ushort* aggb16 = (ushort*)(ws + OFF_AGB);
    ushort* xb = (ushort*)(ws + OFF_XB);

    // zero hist + bn partials
    hipMemsetAsync(ws, 0, (size_t)(NN + 256) * sizeof(float), stream);

    k_hist<<<(NE + 255) / 256, 256, 0, stream>>>(dst, hist);
    k_scan1<<<NSCAN, 1024, 0, stream>>>(hist, offs, bsum);
    k_scan2<<<1, 64, 0, stream>>>(bsum);
    k_scan3<<<NSCAN, 1024, 0, stream>>>(offs, bsum);
    k_reorder<<<(NE + 255) / 256, 256, 0, stream>>>(src, dst, offs, hist, csr);

    if (big) {
        k_cvt<<<(NN * DIN / 8 + 255) / 256, 256, 0, stream>>>(x, xb);
        k_cvtw<<<8, 256, 0, stream>>>(W1l, W1r, wfrag);
        k_agg_bf16<<<(NN * 64 + 255) / 256, 256, 0, stream>>>((const __hip_bfloat16*)xb, offs, csr, aggb16);
        k_mmx<<<512, 256, 0, stream>>>(aggb16, xb, wfrag, b1, h, bnsum, bnsq);
    } else {
        k_agg32<<<(NN * 64 + 255) / 256, 256, 0, stream>>>(x, offs, csr, h);
        k_mm_lds<<<1024, 256, 0, stream>>>(x, W1l, W1r, b1, h, bnsum, bnsq);
    }

    k_bnfin<<<1, 128, 0, stream>>>(bnsum, bnsq, gamma, beta, cA, cC);
    k_proj<<<(NN + 3) / 4, 256, 0, stream>>>(h, cA, cC, W2l, W2r, plr);
    k_out<<<(NN + 255) / 256, 256, 0, stream>>>(plr, offs, csr, b2, out);
}

// Round 8
// 322.727 us; speedup vs baseline: 1.6444x; 1.0786x over previous
//
#include <hip/hip_runtime.h>
#include <hip/hip_bf16.h>

#define NN 100000
#define NE 1000000
#define DIN 64
#define DH 128
#define NSCAN 98   // ceil(NN/1024)
#define NB 98      // dst-buckets of 1024 nodes

typedef __attribute__((ext_vector_type(8))) short short8;
typedef __attribute__((ext_vector_type(4))) float floatx4;

// ---- workspace layout (32-bit words) ----
// hist[NN] | bnsum[128] | bnsq[128] | cA[128] | cC[128] | offs[NN+1]+pad |
// csr[NE] | plr[NN*4] | wfrag[8192] | aggb16[NN*32] | xb[NN*32] | h[NN*128]
// scan partials (98) at plr front; gcur[98] at plr+512; ebuf (2M words) overlays h front.
#define OFF_HIST  0
#define OFF_BNSUM (NN)
#define OFF_BNSQ  (NN + 128)
#define OFF_CA    (NN + 256)
#define OFF_CC    (NN + 384)
#define OFF_OFFS  (NN + 512)
#define OFF_CSR   (OFF_OFFS + NN + 4)
#define OFF_PLR   (OFF_CSR + NE)
#define OFF_WF    (OFF_PLR + NN * 4)
#define OFF_AGB   (OFF_WF + 8192)
#define OFF_XB    (OFF_AGB + NN * 32)
#define OFF_H     (OFF_XB + NN * 32)
#define WORDS_NEEDED ((size_t)OFF_H + (size_t)NN * DH)
#define OFF_H_FB  (OFF_PLR + NN * 4)

static __device__ __forceinline__ float b2f(short s) {
    union { unsigned u; float f; } c;
    c.u = ((unsigned)(unsigned short)s) << 16;
    return c.f;
}

// ---------------- CSR build ----------------
__global__ __launch_bounds__(256) void k_hist(const int* __restrict__ dst, int* __restrict__ hist) {
    int e = blockIdx.x * 256 + threadIdx.x;
    if (e < NE) atomicAdd(&hist[dst[e]], 1);
}

__global__ __launch_bounds__(1024) void k_scan1(const int* __restrict__ hist,
                                                int* __restrict__ offs, int* __restrict__ bsum) {
    __shared__ int tmp[1024];
    int t = threadIdx.x, idx = blockIdx.x * 1024 + t;
    int v = (idx < NN) ? hist[idx] : 0;
    int sum = v;
    tmp[t] = sum;
    __syncthreads();
    for (int off = 1; off < 1024; off <<= 1) {
        int o = (t >= off) ? tmp[t - off] : 0;
        __syncthreads();
        sum += o;
        tmp[t] = sum;
        __syncthreads();
    }
    if (idx < NN) offs[idx] = sum - v;  // local exclusive
    if (t == 1023) bsum[blockIdx.x] = sum;
}

__global__ void k_scan2(int* __restrict__ bsum) {
    if (threadIdx.x == 0) {
        int acc = 0;
        for (int i = 0; i < NSCAN; ++i) { int v = bsum[i]; bsum[i] = acc; acc += v; }
    }
}

__global__ __launch_bounds__(1024) void k_scan3(int* __restrict__ offs, const int* __restrict__ bsum) {
    int t = threadIdx.x, idx = blockIdx.x * 1024 + t;
    if (idx < NN) offs[idx] += bsum[blockIdx.x];
    if (blockIdx.x == 0 && t == 0) offs[NN] = NE;
}

__global__ void k_binit(const int* __restrict__ offs, int* __restrict__ gcur) {
    int t = threadIdx.x;
    if (t < NB) gcur[t] = offs[t * 1024];
}

// R1: scatter (src,dst) into dst-buckets; each block claims CONTIGUOUS slot runs
// per bucket -> full-line writebacks instead of 4B random scatter.
__global__ __launch_bounds__(256) void k_bucket(const int* __restrict__ src,
                                                const int* __restrict__ dst,
                                                int* __restrict__ gcur,
                                                int2* __restrict__ ebuf) {
    __shared__ int lh[NB], lb[NB];
    const int tid = threadIdx.x;
    const int per = (NE + gridDim.x - 1) / gridDim.x;
    const int e0 = blockIdx.x * per, e1 = min(e0 + per, NE);
    if (tid < NB) lh[tid] = 0;
    __syncthreads();
    for (int e = e0 + tid; e < e1; e += 256)
        atomicAdd(&lh[dst[e] >> 10], 1);
    __syncthreads();
    if (tid < NB) { lb[tid] = atomicAdd(&gcur[tid], lh[tid]); lh[tid] = 0; }
    __syncthreads();
    for (int e = e0 + tid; e < e1; e += 256) {
        int d = dst[e];
        int b = d >> 10;
        int slot = lb[b] + atomicAdd(&lh[b], 1);
        ebuf[slot] = make_int2(src[e], d);
    }
}

// R2: one block per bucket; coalesced pair reads, LDS per-node cursors,
// csr writes confined to a ~40KB L2-resident window.
__global__ __launch_bounds__(256) void k_place(const int2* __restrict__ ebuf,
                                               const int* __restrict__ offs,
                                               int* __restrict__ csr) {
    __shared__ int cur[1024];
    const int tid = threadIdx.x;
    const int nb0 = blockIdx.x << 10;
    const int nb1 = min(nb0 + 1024, NN);
    for (int i = tid; i < 1024; i += 256) cur[i] = 0;
    __syncthreads();
    const int ebeg = offs[nb0];
    const int eend = offs[nb1];
    for (int i = ebeg + tid; i < eend; i += 256) {
        int2 e = ebuf[i];
        int slot = offs[e.y] + atomicAdd(&cur[e.y - nb0], 1);
        csr[slot] = e.x;
    }
}

// ---------------- x -> bf16 ----------------
__global__ __launch_bounds__(256) void k_cvt(const float* __restrict__ x,
                                             ushort* __restrict__ xb) {
    int i = blockIdx.x * 256 + threadIdx.x;  // 8 elems each
    if (i >= NN * DIN / 8) return;
    float4 a = *(const float4*)(x + (size_t)i * 8);
    float4 b = *(const float4*)(x + (size_t)i * 8 + 4);
    __hip_bfloat16 o[8];
    o[0] = __float2bfloat16(a.x); o[1] = __float2bfloat16(a.y);
    o[2] = __float2bfloat16(a.z); o[3] = __float2bfloat16(a.w);
    o[4] = __float2bfloat16(b.x); o[5] = __float2bfloat16(b.y);
    o[6] = __float2bfloat16(b.z); o[7] = __float2bfloat16(b.w);
    *(uint4*)&xb[(size_t)i * 8] = *(uint4*)o;
}

// ---------------- weights -> bf16 MFMA B-fragment order ----------------
__global__ __launch_bounds__(256) void k_cvtw(const float* __restrict__ W1l,
                                              const float* __restrict__ W1r,
                                              ushort* __restrict__ wfrag) {
    int t = blockIdx.x * 256 + threadIdx.x;  // 0..2047
    if (t >= 2048) return;
    int ct = t >> 8, ks = (t >> 6) & 3, l = t & 63;
    int k0 = ks * 32 + (l >> 4) * 8;
    int col = ct * 16 + (l & 15);
    ushort o[8];
#pragma unroll
    for (int j = 0; j < 8; ++j) {
        int k = k0 + j;
        float v = (k < 64) ? W1l[k * DH + col] : W1r[(k - 64) * DH + col];
        __hip_bfloat16 b = __float2bfloat16(v);
        o[j] = *(ushort*)&b;
    }
    *(uint4*)&wfrag[(size_t)t * 8] = *(uint4*)o;
}

// ---------------- agg: vectorized CSR gather-mean (16B/lane) ----------------
// wave per node; lane l: neighbor-slot g=l>>3, dim-octet d8=l&7.
// Each lane: one short8 (16B) load per 8-neighbor step; butterfly reduce over g.
__global__ __launch_bounds__(256) void k_aggv(const ushort* __restrict__ xb,
                                              const int* __restrict__ offs,
                                              const int* __restrict__ csr,
                                              ushort* __restrict__ aggb16) {
    int wid = (blockIdx.x * 256 + threadIdx.x) >> 6;  // node
    int l = threadIdx.x & 63;
    if (wid >= NN) return;
    int beg = offs[wid];
    int deg = offs[wid + 1] - beg;
    const int g = l >> 3, d8 = l & 7;
    float a[8] = {0, 0, 0, 0, 0, 0, 0, 0};
    for (int ch = 0; ch < deg; ch += 8) {
        int j = ch + g;
        if (j < deg) {
            int sv = csr[beg + j];
            short8 v = *(const short8*)&xb[(size_t)sv * DIN + d8 * 8];
#pragma unroll
            for (int i = 0; i < 8; ++i) a[i] += b2f(v[i]);
        }
    }
#pragma unroll
    for (int i = 0; i < 8; ++i) {
        a[i] += __shfl_xor(a[i], 8);
        a[i] += __shfl_xor(a[i], 16);
        a[i] += __shfl_xor(a[i], 32);
    }
    if (g == 0) {  // lanes 0..7 write 16B each -> 128B contiguous row
        float inv = 1.f / fmaxf((float)deg, 1.f);
        ushort o[8];
#pragma unroll
        for (int i = 0; i < 8; ++i) {
            __hip_bfloat16 b = __float2bfloat16(a[i] * inv);
            o[i] = *(ushort*)&b;
        }
        *(uint4*)&aggb16[(size_t)wid * DIN + d8 * 8] = *(uint4*)o;
    }
}

// ---------------- MFMA dual-GEMM: h = [agg|x] @ [W1l;W1r] + b1, BN partials ----------------
__global__ __launch_bounds__(256, 2) void k_mmx(const ushort* __restrict__ aggb16,
                                                const ushort* __restrict__ xb,
                                                const ushort* __restrict__ wfrag,
                                                const float* __restrict__ b1,
                                                float* __restrict__ h,
                                                float* __restrict__ bnsum,
                                                float* __restrict__ bnsq) {
    __shared__ ushort sW[16384];     // 32 KB: B-fragments
    __shared__ ushort sA[64 * 136];  // 17 KB: A tile, padded stride 136
    const int tid = threadIdx.x;
    const int l = tid & 63, w = tid >> 6;
    const int r0 = l & 15, kg = l >> 4;

    {  // stage weight fragments once
        const uint4* wsrc = (const uint4*)wfrag;
        uint4* wdst = (uint4*)sW;
#pragma unroll
        for (int i = 0; i < 8; ++i) wdst[tid + i * 256] = wsrc[tid + i * 256];
    }

    float bias8[8];
#pragma unroll
    for (int ct = 0; ct < 8; ++ct) bias8[ct] = b1[ct * 16 + r0];

    float psum8[8] = {0, 0, 0, 0, 0, 0, 0, 0};
    float psq8[8] = {0, 0, 0, 0, 0, 0, 0, 0};

    __syncthreads();

    const int ntiles = (NN + 63) / 64;
    for (int tile = blockIdx.x; tile < ntiles; tile += gridDim.x) {
        const int tb = tile * 64;
#pragma unroll
        for (int i = 0; i < 4; ++i) {
            int f = tid + i * 256;  // 0..1023 16B-chunks
            int row = f >> 4, ch = f & 15;
            const uint4* src = (ch < 8)
                ? (const uint4*)(aggb16 + (size_t)(tb + row) * 64 + ch * 8)
                : (const uint4*)(xb + (size_t)(tb + row) * 64 + (ch - 8) * 8);
            *(uint4*)&sA[row * 136 + ch * 8] = *src;
        }
        __syncthreads();

        short8 af[4];
        const int abase = (w * 16 + r0) * 136 + kg * 8;
#pragma unroll
        for (int ks = 0; ks < 4; ++ks)
            af[ks] = *(const short8*)&sA[abase + ks * 32];

#pragma unroll
        for (int ct = 0; ct < 8; ++ct) {
            floatx4 acc = {0.f, 0.f, 0.f, 0.f};
#pragma unroll
            for (int ks = 0; ks < 4; ++ks) {
                short8 bf = *(const short8*)&sW[((ct * 4 + ks) * 64 + l) * 8];
                acc = __builtin_amdgcn_mfma_f32_16x16x32_bf16(af[ks], bf, acc, 0, 0, 0);
            }
            const int col = ct * 16 + r0;
#pragma unroll
            for (int i = 0; i < 4; ++i) {
                int r = tb + w * 16 + kg * 4 + i;
                if (r < NN) {
                    float o = acc[i] + bias8[ct];
                    h[(size_t)r * DH + col] = o;
                    psum8[ct] += o;
                    psq8[ct] += o * o;
                }
            }
        }
        __syncthreads();
    }

#pragma unroll
    for (int ct = 0; ct < 8; ++ct) {
        float s = psum8[ct], q = psq8[ct];
        s += __shfl_xor(s, 16); s += __shfl_xor(s, 32);
        q += __shfl_xor(q, 16); q += __shfl_xor(q, 32);
        if (l < 16) {
            atomicAdd(&bnsum[ct * 16 + l], s);
            atomicAdd(&bnsq[ct * 16 + l], q);
        }
    }
}

// ---------------- fallback (round-4) agg + LDS GEMM ----------------
__global__ __launch_bounds__(256) void k_agg32(const float* __restrict__ x,
                                               const int* __restrict__ offs,
                                               const int* __restrict__ csr,
                                               float* __restrict__ h) {
    int wid = (blockIdx.x * 256 + threadIdx.x) >> 6;
    int lane = threadIdx.x & 63;
    if (wid >= NN) return;
    int beg = offs[wid];
    int deg = offs[wid + 1] - beg;
    float acc = 0.f;
    for (int ch = 0; ch < deg; ch += 64) {
        int m = min(deg - ch, 64);
        int sv = (lane < m) ? csr[beg + ch + lane] : 0;
        for (int j = 0; j < m; ++j)
            acc += x[(size_t)__shfl(sv, j) * DIN + lane];
    }
    h[(size_t)wid * DH + lane] = acc / fmaxf((float)deg, 1.f);
}

__global__ __launch_bounds__(256, 2) void k_mm_lds(const float* __restrict__ x,
                                                   const float* __restrict__ W1l,
                                                   const float* __restrict__ W1r,
                                                   const float* __restrict__ b1,
                                                   float* h,
                                                   float* __restrict__ bnsum,
                                                   float* __restrict__ bnsq) {
    const int c = threadIdx.x & 127;
    const int sub = threadIdx.x >> 7;
    float wl[DIN], wr[DIN];
#pragma unroll
    for (int k = 0; k < DIN; ++k) {
        wl[k] = W1l[k * DH + c];
        wr[k] = W1r[k * DH + c];
    }
    const float bias = b1[c];
    __shared__ __align__(16) float sA[32][DIN];
    __shared__ __align__(16) float sX[32][DIN];
    float psum = 0.f, psq = 0.f;
    for (int base = blockIdx.x * 32; base < NN; base += gridDim.x * 32) {
        __syncthreads();
#pragma unroll
        for (int i = 0; i < 2; ++i) {
            int f = threadIdx.x + i * 256;
            int row = f >> 4, col = (f & 15) * 4;
            *(float4*)&sA[row][col] = *(const float4*)&h[(size_t)(base + row) * DH + col];
            *(float4*)&sX[row][col] = *(const float4*)&x[(size_t)(base + row) * DIN + col];
        }
        __syncthreads();
        const int nb = sub * 16;
#pragma unroll
        for (int n = 0; n < 16; ++n) {
            float acc = bias;
#pragma unroll
            for (int kk = 0; kk < DIN; kk += 4) {
                float4 a4 = *(const float4*)&sA[nb + n][kk];
                float4 x4 = *(const float4*)&sX[nb + n][kk];
                acc += a4.x * wl[kk] + a4.y * wl[kk + 1] + a4.z * wl[kk + 2] + a4.w * wl[kk + 3];
                acc += x4.x * wr[kk] + x4.y * wr[kk + 1] + x4.z * wr[kk + 2] + x4.w * wr[kk + 3];
            }
            h[(size_t)(base + nb + n) * DH + c] = acc;
            psum += acc;
            psq += acc * acc;
        }
    }
    float* rr = &sA[0][0];
    __syncthreads();
    if (sub == 1) { rr[c] = psum; rr[128 + c] = psq; }
    __syncthreads();
    if (sub == 0) {
        atomicAdd(&bnsum[c], psum + rr[c]);
        atomicAdd(&bnsq[c], psq + rr[128 + c]);
    }
}

// ---------------- fold BN into per-channel affine ----------------
__global__ void k_bnfin(const float* __restrict__ bnsum, const float* __restrict__ bnsq,
                        const float* __restrict__ gamma, const float* __restrict__ beta,
                        float* __restrict__ cA, float* __restrict__ cC) {
    int c = threadIdx.x;
    if (c < DH) {
        float mu = bnsum[c] * (1.f / NN);
        float var = bnsq[c] * (1.f / NN) - mu * mu;
        float a = rsqrtf(var + 1e-5f) * gamma[c];
        cA[c] = a;
        cC[c] = beta[c] - mu * a;
    }
}

// ---------------- per-node projection: plr[n] = {hb@W2l (2), hb@W2r (2)} ----------------
__global__ __launch_bounds__(256) void k_proj(const float* __restrict__ h,
                                              const float* __restrict__ cA,
                                              const float* __restrict__ cC,
                                              const float* __restrict__ W2l,
                                              const float* __restrict__ W2r,
                                              float4* __restrict__ plr) {
    int wid = (blockIdx.x * 256 + threadIdx.x) >> 6;  // node
    int lane = threadIdx.x & 63;
    if (wid >= NN) return;
    int c0 = lane * 2;
    float2 hv = *(const float2*)&h[(size_t)wid * DH + c0];
    float hb0 = fmaxf(hv.x * cA[c0] + cC[c0], 0.f);
    float hb1 = fmaxf(hv.y * cA[c0 + 1] + cC[c0 + 1], 0.f);
    float pl0 = hb0 * W2l[c0 * 2 + 0] + hb1 * W2l[c0 * 2 + 2];
    float pl1 = hb0 * W2l[c0 * 2 + 1] + hb1 * W2l[c0 * 2 + 3];
    float pr0 = hb0 * W2r[c0 * 2 + 0] + hb1 * W2r[c0 * 2 + 2];
    float pr1 = hb0 * W2r[c0 * 2 + 1] + hb1 * W2r[c0 * 2 + 3];
#pragma unroll
    for (int off = 32; off > 0; off >>= 1) {
        pl0 += __shfl_down(pl0, off);
        pl1 += __shfl_down(pl1, off);
        pr0 += __shfl_down(pr0, off);
        pr1 += __shfl_down(pr1, off);
    }
    if (lane == 0) plr[wid] = make_float4(pl0, pl1, pr0, pr1);
}

// ---------------- layer-2 aggregate + output ----------------
__global__ __launch_bounds__(256) void k_out(const float4* __restrict__ plr,
                                             const int* __restrict__ offs,
                                             const int* __restrict__ csr,
                                             const float* __restrict__ b2,
                                             float* __restrict__ out) {
    int d = blockIdx.x * 256 + threadIdx.x;
    if (d >= NN) return;
    int beg = offs[d];
    int deg = offs[d + 1] - beg;
    const float2* pl2 = (const float2*)plr;
    float s0 = 0.f, s1 = 0.f;
    for (int i = 0; i < deg; ++i) {
        int s = csr[beg + i];
        float2 p = pl2[(size_t)s * 2];
        s0 += p.x;
        s1 += p.y;
    }
    float inv = 1.f / fmaxf((float)deg, 1.f);
    float4 me = plr[d];
    out[(size_t)d * 2 + 0] = s0 * inv + me.z + b2[0];
    out[(size_t)d * 2 + 1] = s1 * inv + me.w + b2[1];
}

extern "C" void kernel_launch(void* const* d_in, const int* in_sizes, int n_in,
                              void* d_out, int out_size, void* d_ws, size_t ws_size,
                              hipStream_t stream) {
    const float* x = (const float*)d_in[0];
    const int* ei = (const int*)d_in[1];
    const float* W1l = (const float*)d_in[2];
    const float* W1r = (const float*)d_in[3];
    const float* b1 = (const float*)d_in[4];
    const float* gamma = (const float*)d_in[5];
    const float* beta = (const float*)d_in[6];
    const float* W2l = (const float*)d_in[7];
    const float* W2r = (const float*)d_in[8];
    const float* b2 = (const float*)d_in[9];
    float* out = (float*)d_out;
    float* ws = (float*)d_ws;
    int* wsi = (int*)d_ws;

    const int* src = ei;
    const int* dst = ei + NE;

    int* hist = wsi + OFF_HIST;
    int* offs = wsi + OFF_OFFS;
    int* csr = wsi + OFF_CSR;
    int* bsum = wsi + OFF_PLR;        // scan partials (dead before k_proj)
    int* gcur = wsi + OFF_PLR + 512;  // bucket cursors (dead before k_proj)
    float* bnsum = ws + OFF_BNSUM;
    float* bnsq = ws + OFF_BNSQ;
    float* cA = ws + OFF_CA;
    float* cC = ws + OFF_CC;
    float4* plr = (float4*)(ws + OFF_PLR);

    const bool big = ws_size >= WORDS_NEEDED * sizeof(float);
    float* h = big ? (ws + OFF_H) : (ws + OFF_H_FB);
    int2* ebuf = (int2*)h;  // overlays h front (dead before h is written)
    ushort* wfrag = (ushort*)(ws + OFF_WF);
    ushort* aggb16 = (ushort*)(ws + OFF_AGB);
    ushort* xb = (ushort*)(ws + OFF_XB);

    // zero hist + bn partials
    hipMemsetAsync(ws, 0, (size_t)(NN + 256) * sizeof(float), stream);

    k_hist<<<(NE + 255) / 256, 256, 0, stream>>>(dst, hist);
    k_scan1<<<NSCAN, 1024, 0, stream>>>(hist, offs, bsum);
    k_scan2<<<1, 64, 0, stream>>>(bsum);
    k_scan3<<<NSCAN, 1024, 0, stream>>>(offs, bsum);
    k_binit<<<1, 128, 0, stream>>>(offs, gcur);
    k_bucket<<<256, 256, 0, stream>>>(src, dst, gcur, ebuf);
    k_place<<<NB, 256, 0, stream>>>(ebuf, offs, csr);

    if (big) {
        k_cvt<<<(NN * DIN / 8 + 255) / 256, 256, 0, stream>>>(x, xb);
        k_cvtw<<<8, 256, 0, stream>>>(W1l, W1r, wfrag);
        k_aggv<<<(NN * 64 + 255) / 256, 256, 0, stream>>>(xb, offs, csr, aggb16);
        k_mmx<<<512, 256, 0, stream>>>(aggb16, xb, wfrag, b1, h, bnsum, bnsq);
    } else {
        k_agg32<<<(NN * 64 + 255) / 256, 256, 0, stream>>>(x, offs, csr, h);
        k_mm_lds<<<1024, 256, 0, stream>>>(x, W1l, W1r, b1, h, bnsum, bnsq);
    }

    k_bnfin<<<1, 128, 0, stream>>>(bnsum, bnsq, gamma, beta, cA, cC);
    k_proj<<<(NN + 3) / 4, 256, 0, stream>>>(h, cA, cC, W2l, W2r, plr);
    k_out<<<(NN + 255) / 256, 256, 0, stream>>>(plr, offs, csr, b2, out);
}

// Round 9
// 291.156 us; speedup vs baseline: 1.8227x; 1.1084x over previous
//
#include <hip/hip_runtime.h>
#include <hip/hip_bf16.h>

#define NN 100000
#define NE 1000000
#define DIN 64
#define DH 128
#define NSCAN 98   // ceil(NN/1024)
#define NB 98      // dst-buckets of 1024 nodes
#define NTILES 1563  // ceil(NN/64)

typedef __attribute__((ext_vector_type(8))) short short8;
typedef __attribute__((ext_vector_type(4))) float floatx4;

// ---- workspace layout (32-bit words) ----
// hist[NN] | bnsum[128] | bnsq[128] | cA[128] | cC[128] | offs[NN+1]+pad |
// csr[NE] | plr[NN*4] | wfrag[8192] | aggb16[NN*32] | xb[NN*32] | hb[NN*64 (bf16)]
// scan partials (98) at plr front; gcur[98] at plr+512; ebuf (2M words) overlays hb front.
#define OFF_HIST  0
#define OFF_BNSUM (NN)
#define OFF_BNSQ  (NN + 128)
#define OFF_CA    (NN + 256)
#define OFF_CC    (NN + 384)
#define OFF_OFFS  (NN + 512)
#define OFF_CSR   (OFF_OFFS + NN + 4)
#define OFF_PLR   (OFF_CSR + NE)
#define OFF_WF    (OFF_PLR + NN * 4)
#define OFF_AGB   (OFF_WF + 8192)
#define OFF_XB    (OFF_AGB + NN * 32)
#define OFF_H     (OFF_XB + NN * 32)

static __device__ __forceinline__ float b2f(short s) {
    union { unsigned u; float f; } c;
    c.u = ((unsigned)(unsigned short)s) << 16;
    return c.f;
}

// ---------------- CSR build ----------------
__global__ __launch_bounds__(256) void k_hist(const int* __restrict__ dst, int* __restrict__ hist) {
    int e = blockIdx.x * 256 + threadIdx.x;
    if (e < NE) atomicAdd(&hist[dst[e]], 1);
}

__global__ __launch_bounds__(1024) void k_scan1(const int* __restrict__ hist,
                                                int* __restrict__ offs, int* __restrict__ bsum) {
    __shared__ int tmp[1024];
    int t = threadIdx.x, idx = blockIdx.x * 1024 + t;
    int v = (idx < NN) ? hist[idx] : 0;
    int sum = v;
    tmp[t] = sum;
    __syncthreads();
    for (int off = 1; off < 1024; off <<= 1) {
        int o = (t >= off) ? tmp[t - off] : 0;
        __syncthreads();
        sum += o;
        tmp[t] = sum;
        __syncthreads();
    }
    if (idx < NN) offs[idx] = sum - v;  // local exclusive
    if (t == 1023) bsum[blockIdx.x] = sum;
}

__global__ void k_scan2(int* __restrict__ bsum) {
    if (threadIdx.x == 0) {
        int acc = 0;
        for (int i = 0; i < NSCAN; ++i) { int v = bsum[i]; bsum[i] = acc; acc += v; }
    }
}

__global__ __launch_bounds__(1024) void k_scan3(int* __restrict__ offs, const int* __restrict__ bsum) {
    int t = threadIdx.x, idx = blockIdx.x * 1024 + t;
    if (idx < NN) offs[idx] += bsum[blockIdx.x];
    if (blockIdx.x == 0 && t == 0) offs[NN] = NE;
}

__global__ void k_binit(const int* __restrict__ offs, int* __restrict__ gcur) {
    int t = threadIdx.x;
    if (t < NB) gcur[t] = offs[t * 1024];
}

// R1: scatter (src,dst) into dst-buckets; each block claims CONTIGUOUS slot runs.
__global__ __launch_bounds__(256) void k_bucket(const int* __restrict__ src,
                                                const int* __restrict__ dst,
                                                int* __restrict__ gcur,
                                                int2* __restrict__ ebuf) {
    __shared__ int lh[NB], lb[NB];
    const int tid = threadIdx.x;
    const int per = (NE + gridDim.x - 1) / gridDim.x;
    const int e0 = blockIdx.x * per, e1 = min(e0 + per, NE);
    if (tid < NB) lh[tid] = 0;
    __syncthreads();
    for (int e = e0 + tid; e < e1; e += 256)
        atomicAdd(&lh[dst[e] >> 10], 1);
    __syncthreads();
    if (tid < NB) { lb[tid] = atomicAdd(&gcur[tid], lh[tid]); lh[tid] = 0; }
    __syncthreads();
    for (int e = e0 + tid; e < e1; e += 256) {
        int d = dst[e];
        int b = d >> 10;
        int slot = lb[b] + atomicAdd(&lh[b], 1);
        ebuf[slot] = make_int2(src[e], d);
    }
}

// R2: one block per bucket; LDS per-node cursors; csr writes stay L2-resident.
__global__ __launch_bounds__(256) void k_place(const int2* __restrict__ ebuf,
                                               const int* __restrict__ offs,
                                               int* __restrict__ csr) {
    __shared__ int cur[1024];
    const int tid = threadIdx.x;
    const int nb0 = blockIdx.x << 10;
    const int nb1 = min(nb0 + 1024, NN);
    for (int i = tid; i < 1024; i += 256) cur[i] = 0;
    __syncthreads();
    const int ebeg = offs[nb0];
    const int eend = offs[nb1];
    for (int i = ebeg + tid; i < eend; i += 256) {
        int2 e = ebuf[i];
        int slot = offs[e.y] + atomicAdd(&cur[e.y - nb0], 1);
        csr[slot] = e.x;
    }
}

// ---------------- x -> bf16 ----------------
__global__ __launch_bounds__(256) void k_cvt(const float* __restrict__ x,
                                             ushort* __restrict__ xb) {
    int i = blockIdx.x * 256 + threadIdx.x;  // 8 elems each
    if (i >= NN * DIN / 8) return;
    float4 a = *(const float4*)(x + (size_t)i * 8);
    float4 b = *(const float4*)(x + (size_t)i * 8 + 4);
    __hip_bfloat16 o[8];
    o[0] = __float2bfloat16(a.x); o[1] = __float2bfloat16(a.y);
    o[2] = __float2bfloat16(a.z); o[3] = __float2bfloat16(a.w);
    o[4] = __float2bfloat16(b.x); o[5] = __float2bfloat16(b.y);
    o[6] = __float2bfloat16(b.z); o[7] = __float2bfloat16(b.w);
    *(uint4*)&xb[(size_t)i * 8] = *(uint4*)o;
}

// ---------------- weights -> bf16 MFMA B-fragment order ----------------
// wfrag[((ct*4+ks)*64 + l)*8 + j] = Wcat[ks*32 + (l>>4)*8 + j][ct*16 + (l&15)]
__global__ __launch_bounds__(256) void k_cvtw(const float* __restrict__ W1l,
                                              const float* __restrict__ W1r,
                                              ushort* __restrict__ wfrag) {
    int t = blockIdx.x * 256 + threadIdx.x;  // 0..2047
    if (t >= 2048) return;
    int ct = t >> 8, ks = (t >> 6) & 3, l = t & 63;
    int k0 = ks * 32 + (l >> 4) * 8;
    int col = ct * 16 + (l & 15);
    ushort o[8];
#pragma unroll
    for (int j = 0; j < 8; ++j) {
        int k = k0 + j;
        float v = (k < 64) ? W1l[k * DH + col] : W1r[(k - 64) * DH + col];
        __hip_bfloat16 b = __float2bfloat16(v);
        o[j] = *(ushort*)&b;
    }
    *(uint4*)&wfrag[(size_t)t * 8] = *(uint4*)o;
}

// ---------------- agg: vectorized CSR gather-mean (16B/lane) ----------------
__global__ __launch_bounds__(256) void k_aggv(const ushort* __restrict__ xb,
                                              const int* __restrict__ offs,
                                              const int* __restrict__ csr,
                                              ushort* __restrict__ aggb16) {
    int wid = (blockIdx.x * 256 + threadIdx.x) >> 6;  // node
    int l = threadIdx.x & 63;
    if (wid >= NN) return;
    int beg = offs[wid];
    int deg = offs[wid + 1] - beg;
    const int g = l >> 3, d8 = l & 7;
    float a[8] = {0, 0, 0, 0, 0, 0, 0, 0};
    for (int ch = 0; ch < deg; ch += 8) {
        int j = ch + g;
        if (j < deg) {
            int sv = csr[beg + j];
            short8 v = *(const short8*)&xb[(size_t)sv * DIN + d8 * 8];
#pragma unroll
            for (int i = 0; i < 8; ++i) a[i] += b2f(v[i]);
        }
    }
#pragma unroll
    for (int i = 0; i < 8; ++i) {
        a[i] += __shfl_xor(a[i], 8);
        a[i] += __shfl_xor(a[i], 16);
        a[i] += __shfl_xor(a[i], 32);
    }
    if (g == 0) {  // lanes 0..7 write 16B each -> 128B contiguous row
        float inv = 1.f / fmaxf((float)deg, 1.f);
        ushort o[8];
#pragma unroll
        for (int i = 0; i < 8; ++i) {
            __hip_bfloat16 b = __float2bfloat16(a[i] * inv);
            o[i] = *(ushort*)&b;
        }
        *(uint4*)&aggb16[(size_t)wid * DIN + d8 * 8] = *(uint4*)o;
    }
}

// ---------------- MFMA dual-GEMM: hb = bf16([agg|x] @ [W1l;W1r] + b1), BN partials ----
// B-frags in REGISTERS (wave w owns ct = {2w, 2w+1} -> 8 frags, 32 VGPRs).
// LDS = A-tile only (17 KB) -> ~4 blocks/CU occupancy.
// A-frag: row=lane%16, k=(lane/16)*8+j.  D: col(channel)=lane&15, row(node)=(lane>>4)*4+i.
__global__ __launch_bounds__(256, 4) void k_mmx(const ushort* __restrict__ aggb16,
                                                const ushort* __restrict__ xb,
                                                const ushort* __restrict__ wfrag,
                                                const float* __restrict__ b1,
                                                ushort* __restrict__ hb,
                                                float* __restrict__ bnsum,
                                                float* __restrict__ bnsq) {
    __shared__ ushort sA[64 * 136];  // 17 KB, padded stride 136
    const int tid = threadIdx.x;
    const int l = tid & 63, w = tid >> 6;
    const int r0 = l & 15, kg = l >> 4;

    short8 bf[2][4];
#pragma unroll
    for (int c = 0; c < 2; ++c)
#pragma unroll
        for (int ks = 0; ks < 4; ++ks)
            bf[c][ks] = *(const short8*)&wfrag[(((2 * w + c) * 4 + ks) * 64 + l) * 8];

    float bias2[2];
    bias2[0] = b1[(2 * w) * 16 + r0];
    bias2[1] = b1[(2 * w + 1) * 16 + r0];

    float psum2[2] = {0.f, 0.f}, psq2[2] = {0.f, 0.f};

    for (int tile = blockIdx.x; tile < NTILES; tile += gridDim.x) {
        const int tb = tile * 64;
        __syncthreads();  // prior-iter sA readers done
#pragma unroll
        for (int i = 0; i < 4; ++i) {
            int f = tid + i * 256;  // 0..1023 16B-chunks
            int row = f >> 4, ch = f & 15;
            const uint4* src = (ch < 8)
                ? (const uint4*)(aggb16 + (size_t)(tb + row) * 64 + ch * 8)
                : (const uint4*)(xb + (size_t)(tb + row) * 64 + (ch - 8) * 8);
            *(uint4*)&sA[row * 136 + ch * 8] = *src;
        }
        __syncthreads();

#pragma unroll
        for (int s = 0; s < 4; ++s) {
            short8 af[4];
            const int abase = (s * 16 + r0) * 136 + kg * 8;
#pragma unroll
            for (int ks = 0; ks < 4; ++ks)
                af[ks] = *(const short8*)&sA[abase + ks * 32];
#pragma unroll
            for (int c = 0; c < 2; ++c) {
                floatx4 acc = {0.f, 0.f, 0.f, 0.f};
#pragma unroll
                for (int ks = 0; ks < 4; ++ks)
                    acc = __builtin_amdgcn_mfma_f32_16x16x32_bf16(af[ks], bf[c][ks], acc, 0, 0, 0);
                const int col = (2 * w + c) * 16 + r0;
#pragma unroll
                for (int i = 0; i < 4; ++i) {
                    int r = tb + s * 16 + kg * 4 + i;
                    if (r < NN) {
                        float o = acc[i] + bias2[c];
                        __hip_bfloat16 ob = __float2bfloat16(o);
                        hb[(size_t)r * DH + col] = *(ushort*)&ob;
                        psum2[c] += o;
                        psq2[c] += o * o;
                    }
                }
            }
        }
    }

#pragma unroll
    for (int c = 0; c < 2; ++c) {
        float s = psum2[c], q = psq2[c];
        s += __shfl_xor(s, 16); s += __shfl_xor(s, 32);
        q += __shfl_xor(q, 16); q += __shfl_xor(q, 32);
        if (kg == 0) {  // lanes 0..15, channels disjoint across waves
            atomicAdd(&bnsum[(2 * w + c) * 16 + r0], s);
            atomicAdd(&bnsq[(2 * w + c) * 16 + r0], q);
        }
    }
}

// ---------------- fold BN into per-channel affine ----------------
__global__ void k_bnfin(const float* __restrict__ bnsum, const float* __restrict__ bnsq,
                        const float* __restrict__ gamma, const float* __restrict__ beta,
                        float* __restrict__ cA, float* __restrict__ cC) {
    int c = threadIdx.x;
    if (c < DH) {
        float mu = bnsum[c] * (1.f / NN);
        float var = bnsq[c] * (1.f / NN) - mu * mu;
        float a = rsqrtf(var + 1e-5f) * gamma[c];
        cA[c] = a;
        cC[c] = beta[c] - mu * a;
    }
}

// ---------------- per-node projection from bf16 h ----------------
__global__ __launch_bounds__(256) void k_proj(const ushort* __restrict__ hb,
                                              const float* __restrict__ cA,
                                              const float* __restrict__ cC,
                                              const float* __restrict__ W2l,
                                              const float* __restrict__ W2r,
                                              float4* __restrict__ plr) {
    int wid = (blockIdx.x * 256 + threadIdx.x) >> 6;  // node
    int lane = threadIdx.x & 63;
    if (wid >= NN) return;
    int c0 = lane * 2;
    uint hv = *(const uint*)&hb[(size_t)wid * DH + c0];
    float h0 = b2f((short)(hv & 0xffff));
    float h1 = b2f((short)(hv >> 16));
    float hb0 = fmaxf(h0 * cA[c0] + cC[c0], 0.f);
    float hb1 = fmaxf(h1 * cA[c0 + 1] + cC[c0 + 1], 0.f);
    float pl0 = hb0 * W2l[c0 * 2 + 0] + hb1 * W2l[c0 * 2 + 2];
    float pl1 = hb0 * W2l[c0 * 2 + 1] + hb1 * W2l[c0 * 2 + 3];
    float pr0 = hb0 * W2r[c0 * 2 + 0] + hb1 * W2r[c0 * 2 + 2];
    float pr1 = hb0 * W2r[c0 * 2 + 1] + hb1 * W2r[c0 * 2 + 3];
#pragma unroll
    for (int off = 32; off > 0; off >>= 1) {
        pl0 += __shfl_down(pl0, off);
        pl1 += __shfl_down(pl1, off);
        pr0 += __shfl_down(pr0, off);
        pr1 += __shfl_down(pr1, off);
    }
    if (lane == 0) plr[wid] = make_float4(pl0, pl1, pr0, pr1);
}

// ---------------- layer-2 aggregate + output ----------------
__global__ __launch_bounds__(256) void k_out(const float4* __restrict__ plr,
                                             const int* __restrict__ offs,
                                             const int* __restrict__ csr,
                                             const float* __restrict__ b2,
                                             float* __restrict__ out) {
    int d = blockIdx.x * 256 + threadIdx.x;
    if (d >= NN) return;
    int beg = offs[d];
    int deg = offs[d + 1] - beg;
    const float2* pl2 = (const float2*)plr;
    float s0 = 0.f, s1 = 0.f;
    for (int i = 0; i < deg; ++i) {
        int s = csr[beg + i];
        float2 p = pl2[(size_t)s * 2];
        s0 += p.x;
        s1 += p.y;
    }
    float inv = 1.f / fmaxf((float)deg, 1.f);
    float4 me = plr[d];
    out[(size_t)d * 2 + 0] = s0 * inv + me.z + b2[0];
    out[(size_t)d * 2 + 1] = s1 * inv + me.w + b2[1];
}

extern "C" void kernel_launch(void* const* d_in, const int* in_sizes, int n_in,
                              void* d_out, int out_size, void* d_ws, size_t ws_size,
                              hipStream_t stream) {
    const float* x = (const float*)d_in[0];
    const int* ei = (const int*)d_in[1];
    const float* W1l = (const float*)d_in[2];
    const float* W1r = (const float*)d_in[3];
    const float* b1 = (const float*)d_in[4];
    const float* gamma = (const float*)d_in[5];
    const float* beta = (const float*)d_in[6];
    const float* W2l = (const float*)d_in[7];
    const float* W2r = (const float*)d_in[8];
    const float* b2 = (const float*)d_in[9];
    float* out = (float*)d_out;
    float* ws = (float*)d_ws;
    int* wsi = (int*)d_ws;

    const int* src = ei;
    const int* dst = ei + NE;

    int* hist = wsi + OFF_HIST;
    int* offs = wsi + OFF_OFFS;
    int* csr = wsi + OFF_CSR;
    int* bsum = wsi + OFF_PLR;        // scan partials (dead before k_proj)
    int* gcur = wsi + OFF_PLR + 512;  // bucket cursors (dead before k_proj)
    float* bnsum = ws + OFF_BNSUM;
    float* bnsq = ws + OFF_BNSQ;
    float* cA = ws + OFF_CA;
    float* cC = ws + OFF_CC;
    float4* plr = (float4*)(ws + OFF_PLR);

    ushort* hb = (ushort*)(ws + OFF_H);
    int2* ebuf = (int2*)(ws + OFF_H);  // overlays hb (dead before hb is written)
    ushort* wfrag = (ushort*)(ws + OFF_WF);
    ushort* aggb16 = (ushort*)(ws + OFF_AGB);
    ushort* xb = (ushort*)(ws + OFF_XB);

    // zero hist + bn partials
    hipMemsetAsync(ws, 0, (size_t)(NN + 256) * sizeof(float), stream);

    k_hist<<<(NE + 255) / 256, 256, 0, stream>>>(dst, hist);
    k_scan1<<<NSCAN, 1024, 0, stream>>>(hist, offs, bsum);
    k_scan2<<<1, 64, 0, stream>>>(bsum);
    k_scan3<<<NSCAN, 1024, 0, stream>>>(offs, bsum);
    k_binit<<<1, 128, 0, stream>>>(offs, gcur);
    k_bucket<<<256, 256, 0, stream>>>(src, dst, gcur, ebuf);
    k_place<<<NB, 256, 0, stream>>>(ebuf, offs, csr);

    k_cvt<<<(NN * DIN / 8 + 255) / 256, 256, 0, stream>>>(x, xb);
    k_cvtw<<<8, 256, 0, stream>>>(W1l, W1r, wfrag);
    k_aggv<<<(NN * 64 + 255) / 256, 256, 0, stream>>>(xb, offs, csr, aggb16);
    k_mmx<<<782, 256, 0, stream>>>(aggb16, xb, wfrag, b1, hb, bnsum, bnsq);

    k_bnfin<<<1, 128, 0, stream>>>(bnsum, bnsq, gamma, beta, cA, cC);
    k_proj<<<(NN + 3) / 4, 256, 0, stream>>>(hb, cA, cC, W2l, W2r, plr);
    k_out<<<(NN + 255) / 256, 256, 0, stream>>>(plr, offs, csr, b2, out);
}

// Round 10
// 273.237 us; speedup vs baseline: 1.9422x; 1.0656x over previous
//
#include <hip/hip_runtime.h>
#include <hip/hip_bf16.h>

#define NN 100000
#define NE 1000000
#define DIN 64
#define DH 128
#define NSCAN 98   // ceil(NN/1024)
#define NB 98      // dst-buckets of 1024 nodes
#define NTILES 1563  // ceil(NN/64)

typedef __attribute__((ext_vector_type(8))) short short8;
typedef __attribute__((ext_vector_type(4))) float floatx4;

// ---- workspace layout (32-bit words) ----
// hist[NN] | bnsum[128] | bnsq[128] | cA[128] | cC[128] | offs[NN+1]+pad |
// csr[NE] | plr[NN*4] | wfrag[8192] | aggb16[NN*32] | xb[NN*32] | hb[NN*64 (bf16)]
// scan partials (98) at plr front; gcur[98] at plr+512; ebuf (2M words) overlays hb front.
#define OFF_HIST  0
#define OFF_BNSUM (NN)
#define OFF_BNSQ  (NN + 128)
#define OFF_CA    (NN + 256)
#define OFF_CC    (NN + 384)
#define OFF_OFFS  (NN + 512)
#define OFF_CSR   (OFF_OFFS + NN + 4)
#define OFF_PLR   (OFF_CSR + NE)
#define OFF_WF    (OFF_PLR + NN * 4)
#define OFF_AGB   (OFF_WF + 8192)
#define OFF_XB    (OFF_AGB + NN * 32)
#define OFF_H     (OFF_XB + NN * 32)

static __device__ __forceinline__ float b2f(short s) {
    union { unsigned u; float f; } c;
    c.u = ((unsigned)(unsigned short)s) << 16;
    return c.f;
}

// ---------------- fused prep: edge histogram + x->bf16 + weight fragments ----------------
// disjoint thread-range jobs, no ordering dependencies.
__global__ __launch_bounds__(256) void k_prep(const int* __restrict__ dst,
                                              const float* __restrict__ x,
                                              const float* __restrict__ W1l,
                                              const float* __restrict__ W1r,
                                              int* __restrict__ hist,
                                              ushort* __restrict__ xb,
                                              ushort* __restrict__ wfrag) {
    int t = blockIdx.x * 256 + threadIdx.x;
    if (t < NE) atomicAdd(&hist[dst[t]], 1);
    if (t < NN * DIN / 8) {
        float4 a = *(const float4*)(x + (size_t)t * 8);
        float4 b = *(const float4*)(x + (size_t)t * 8 + 4);
        __hip_bfloat16 o[8];
        o[0] = __float2bfloat16(a.x); o[1] = __float2bfloat16(a.y);
        o[2] = __float2bfloat16(a.z); o[3] = __float2bfloat16(a.w);
        o[4] = __float2bfloat16(b.x); o[5] = __float2bfloat16(b.y);
        o[6] = __float2bfloat16(b.z); o[7] = __float2bfloat16(b.w);
        *(uint4*)&xb[(size_t)t * 8] = *(uint4*)o;
    }
    if (t < 2048) {  // wfrag[((ct*4+ks)*64+l)*8+j] = Wcat[ks*32+(l>>4)*8+j][ct*16+(l&15)]
        int ct = t >> 8, ks = (t >> 6) & 3, l = t & 63;
        int k0 = ks * 32 + (l >> 4) * 8;
        int col = ct * 16 + (l & 15);
        ushort o[8];
#pragma unroll
        for (int j = 0; j < 8; ++j) {
            int k = k0 + j;
            float v = (k < 64) ? W1l[k * DH + col] : W1r[(k - 64) * DH + col];
            __hip_bfloat16 b = __float2bfloat16(v);
            o[j] = *(ushort*)&b;
        }
        *(uint4*)&wfrag[(size_t)t * 8] = *(uint4*)o;
    }
}

// ---------------- CSR scan ----------------
__global__ __launch_bounds__(1024) void k_scan1(const int* __restrict__ hist,
                                                int* __restrict__ offs, int* __restrict__ bsum) {
    __shared__ int tmp[1024];
    int t = threadIdx.x, idx = blockIdx.x * 1024 + t;
    int v = (idx < NN) ? hist[idx] : 0;
    int sum = v;
    tmp[t] = sum;
    __syncthreads();
    for (int off = 1; off < 1024; off <<= 1) {
        int o = (t >= off) ? tmp[t - off] : 0;
        __syncthreads();
        sum += o;
        tmp[t] = sum;
        __syncthreads();
    }
    if (idx < NN) offs[idx] = sum - v;  // local exclusive
    if (t == 1023) bsum[blockIdx.x] = sum;
}

// scan3 absorbs scan2 (in-block prefix of the 98 block sums) and binit (gcur).
__global__ __launch_bounds__(1024) void k_scan3(int* __restrict__ offs,
                                                const int* __restrict__ bsum,
                                                int* __restrict__ gcur) {
    __shared__ int pre[NSCAN];
    int t = threadIdx.x;
    if (t < NSCAN) pre[t] = bsum[t];
    __syncthreads();
    if (t == 0) {
        int acc = 0;
        for (int i = 0; i < NSCAN; ++i) { int v = pre[i]; pre[i] = acc; acc += v; }
    }
    __syncthreads();
    int idx = blockIdx.x * 1024 + t;
    if (idx < NN) offs[idx] += pre[blockIdx.x];
    if (blockIdx.x == 0) {
        if (t == 0) offs[NN] = NE;
        if (t < NSCAN) gcur[t] = pre[t];  // final offs[t*1024] == pre[t]
    }
}

// R1: scatter (src,dst) into dst-buckets; each block claims CONTIGUOUS slot runs.
__global__ __launch_bounds__(256) void k_bucket(const int* __restrict__ src,
                                                const int* __restrict__ dst,
                                                int* __restrict__ gcur,
                                                int2* __restrict__ ebuf) {
    __shared__ int lh[NB], lb[NB];
    const int tid = threadIdx.x;
    const int per = (NE + gridDim.x - 1) / gridDim.x;
    const int e0 = blockIdx.x * per, e1 = min(e0 + per, NE);
    if (tid < NB) lh[tid] = 0;
    __syncthreads();
    for (int e = e0 + tid; e < e1; e += 256)
        atomicAdd(&lh[dst[e] >> 10], 1);
    __syncthreads();
    if (tid < NB) { lb[tid] = atomicAdd(&gcur[tid], lh[tid]); lh[tid] = 0; }
    __syncthreads();
    for (int e = e0 + tid; e < e1; e += 256) {
        int d = dst[e];
        int b = d >> 10;
        int slot = lb[b] + atomicAdd(&lh[b], 1);
        ebuf[slot] = make_int2(src[e], d);
    }
}

// R2: one block per bucket; LDS per-node cursors; csr writes stay L2-resident.
__global__ __launch_bounds__(1024) void k_place(const int2* __restrict__ ebuf,
                                                const int* __restrict__ offs,
                                                int* __restrict__ csr) {
    __shared__ int cur[1024];
    const int tid = threadIdx.x;
    const int nb0 = blockIdx.x << 10;
    const int nb1 = min(nb0 + 1024, NN);
    cur[tid] = 0;
    __syncthreads();
    const int ebeg = offs[nb0];
    const int eend = offs[nb1];
    for (int i = ebeg + tid; i < eend; i += 1024) {
        int2 e = ebuf[i];
        int slot = offs[e.y] + atomicAdd(&cur[e.y - nb0], 1);
        csr[slot] = e.x;
    }
}

// ---------------- agg: vectorized CSR gather-mean (16B/lane) ----------------
__global__ __launch_bounds__(256) void k_aggv(const ushort* __restrict__ xb,
                                              const int* __restrict__ offs,
                                              const int* __restrict__ csr,
                                              ushort* __restrict__ aggb16) {
    int wid = (blockIdx.x * 256 + threadIdx.x) >> 6;  // node
    int l = threadIdx.x & 63;
    if (wid >= NN) return;
    int beg = offs[wid];
    int deg = offs[wid + 1] - beg;
    const int g = l >> 3, d8 = l & 7;
    float a[8] = {0, 0, 0, 0, 0, 0, 0, 0};
    for (int ch = 0; ch < deg; ch += 8) {
        int j = ch + g;
        if (j < deg) {
            int sv = csr[beg + j];
            short8 v = *(const short8*)&xb[(size_t)sv * DIN + d8 * 8];
#pragma unroll
            for (int i = 0; i < 8; ++i) a[i] += b2f(v[i]);
        }
    }
#pragma unroll
    for (int i = 0; i < 8; ++i) {
        a[i] += __shfl_xor(a[i], 8);
        a[i] += __shfl_xor(a[i], 16);
        a[i] += __shfl_xor(a[i], 32);
    }
    if (g == 0) {  // lanes 0..7 write 16B each -> 128B contiguous row
        float inv = 1.f / fmaxf((float)deg, 1.f);
        ushort o[8];
#pragma unroll
        for (int i = 0; i < 8; ++i) {
            __hip_bfloat16 b = __float2bfloat16(a[i] * inv);
            o[i] = *(ushort*)&b;
        }
        *(uint4*)&aggb16[(size_t)wid * DIN + d8 * 8] = *(uint4*)o;
    }
}

// ---------------- MFMA dual-GEMM: hb = bf16([agg|x] @ [W1l;W1r] + b1), BN partials ----
// B-frags in registers (wave w owns ct = {2w, 2w+1}); LDS = A-tile only (17 KB).
__global__ __launch_bounds__(256, 4) void k_mmx(const ushort* __restrict__ aggb16,
                                                const ushort* __restrict__ xb,
                                                const ushort* __restrict__ wfrag,
                                                const float* __restrict__ b1,
                                                ushort* __restrict__ hb,
                                                float* __restrict__ bnsum,
                                                float* __restrict__ bnsq) {
    __shared__ ushort sA[64 * 136];  // 17 KB, padded stride 136
    const int tid = threadIdx.x;
    const int l = tid & 63, w = tid >> 6;
    const int r0 = l & 15, kg = l >> 4;

    short8 bf[2][4];
#pragma unroll
    for (int c = 0; c < 2; ++c)
#pragma unroll
        for (int ks = 0; ks < 4; ++ks)
            bf[c][ks] = *(const short8*)&wfrag[(((2 * w + c) * 4 + ks) * 64 + l) * 8];

    float bias2[2];
    bias2[0] = b1[(2 * w) * 16 + r0];
    bias2[1] = b1[(2 * w + 1) * 16 + r0];

    float psum2[2] = {0.f, 0.f}, psq2[2] = {0.f, 0.f};

    for (int tile = blockIdx.x; tile < NTILES; tile += gridDim.x) {
        const int tb = tile * 64;
        __syncthreads();  // prior-iter sA readers done
#pragma unroll
        for (int i = 0; i < 4; ++i) {
            int f = tid + i * 256;  // 0..1023 16B-chunks
            int row = f >> 4, ch = f & 15;
            const uint4* src = (ch < 8)
                ? (const uint4*)(aggb16 + (size_t)(tb + row) * 64 + ch * 8)
                : (const uint4*)(xb + (size_t)(tb + row) * 64 + (ch - 8) * 8);
            *(uint4*)&sA[row * 136 + ch * 8] = *src;
        }
        __syncthreads();

#pragma unroll
        for (int s = 0; s < 4; ++s) {
            short8 af[4];
            const int abase = (s * 16 + r0) * 136 + kg * 8;
#pragma unroll
            for (int ks = 0; ks < 4; ++ks)
                af[ks] = *(const short8*)&sA[abase + ks * 32];
#pragma unroll
            for (int c = 0; c < 2; ++c) {
                floatx4 acc = {0.f, 0.f, 0.f, 0.f};
#pragma unroll
                for (int ks = 0; ks < 4; ++ks)
                    acc = __builtin_amdgcn_mfma_f32_16x16x32_bf16(af[ks], bf[c][ks], acc, 0, 0, 0);
                const int col = (2 * w + c) * 16 + r0;
#pragma unroll
                for (int i = 0; i < 4; ++i) {
                    int r = tb + s * 16 + kg * 4 + i;
                    if (r < NN) {
                        float o = acc[i] + bias2[c];
                        __hip_bfloat16 ob = __float2bfloat16(o);
                        hb[(size_t)r * DH + col] = *(ushort*)&ob;
                        psum2[c] += o;
                        psq2[c] += o * o;
                    }
                }
            }
        }
    }

#pragma unroll
    for (int c = 0; c < 2; ++c) {
        float s = psum2[c], q = psq2[c];
        s += __shfl_xor(s, 16); s += __shfl_xor(s, 32);
        q += __shfl_xor(q, 16); q += __shfl_xor(q, 32);
        if (kg == 0) {  // lanes 0..15, channels disjoint across waves
            atomicAdd(&bnsum[(2 * w + c) * 16 + r0], s);
            atomicAdd(&bnsq[(2 * w + c) * 16 + r0], q);
        }
    }
}

// ---------------- per-node projection (BN affine computed per-block in LDS) ----------------
__global__ __launch_bounds__(256) void k_proj(const ushort* __restrict__ hb,
                                              const float* __restrict__ bnsum,
                                              const float* __restrict__ bnsq,
                                              const float* __restrict__ gamma,
                                              const float* __restrict__ beta,
                                              const float* __restrict__ W2l,
                                              const float* __restrict__ W2r,
                                              float4* __restrict__ plr) {
    __shared__ float sCA[DH], sCC[DH];
    int tid = threadIdx.x;
    if (tid < DH) {
        float mu = bnsum[tid] * (1.f / NN);
        float var = bnsq[tid] * (1.f / NN) - mu * mu;
        float a = rsqrtf(var + 1e-5f) * gamma[tid];
        sCA[tid] = a;
        sCC[tid] = beta[tid] - mu * a;
    }
    __syncthreads();
    int wid = (blockIdx.x * 256 + tid) >> 6;  // node
    int lane = tid & 63;
    if (wid >= NN) return;
    int c0 = lane * 2;
    uint hv = *(const uint*)&hb[(size_t)wid * DH + c0];
    float h0 = b2f((short)(hv & 0xffff));
    float h1 = b2f((short)(hv >> 16));
    float hb0 = fmaxf(h0 * sCA[c0] + sCC[c0], 0.f);
    float hb1 = fmaxf(h1 * sCA[c0 + 1] + sCC[c0 + 1], 0.f);
    float pl0 = hb0 * W2l[c0 * 2 + 0] + hb1 * W2l[c0 * 2 + 2];
    float pl1 = hb0 * W2l[c0 * 2 + 1] + hb1 * W2l[c0 * 2 + 3];
    float pr0 = hb0 * W2r[c0 * 2 + 0] + hb1 * W2r[c0 * 2 + 2];
    float pr1 = hb0 * W2r[c0 * 2 + 1] + hb1 * W2r[c0 * 2 + 3];
#pragma unroll
    for (int off = 32; off > 0; off >>= 1) {
        pl0 += __shfl_down(pl0, off);
        pl1 += __shfl_down(pl1, off);
        pr0 += __shfl_down(pr0, off);
        pr1 += __shfl_down(pr1, off);
    }
    if (lane == 0) plr[wid] = make_float4(pl0, pl1, pr0, pr1);
}

// ---------------- layer-2 aggregate + output (4-way unrolled gather) ----------------
__global__ __launch_bounds__(256) void k_out(const float4* __restrict__ plr,
                                             const int* __restrict__ offs,
                                             const int* __restrict__ csr,
                                             const float* __restrict__ b2,
                                             float* __restrict__ out) {
    int d = blockIdx.x * 256 + threadIdx.x;
    if (d >= NN) return;
    int beg = offs[d];
    int deg = offs[d + 1] - beg;
    const float2* pl2 = (const float2*)plr;
    float s0 = 0.f, s1 = 0.f;
    int i = 0;
    for (; i + 4 <= deg; i += 4) {
        int n0 = csr[beg + i], n1 = csr[beg + i + 1];
        int n2 = csr[beg + i + 2], n3 = csr[beg + i + 3];
        float2 p0 = pl2[(size_t)n0 * 2];
        float2 p1 = pl2[(size_t)n1 * 2];
        float2 p2 = pl2[(size_t)n2 * 2];
        float2 p3 = pl2[(size_t)n3 * 2];
        s0 += (p0.x + p1.x) + (p2.x + p3.x);
        s1 += (p0.y + p1.y) + (p2.y + p3.y);
    }
    for (; i < deg; ++i) {
        float2 p = pl2[(size_t)csr[beg + i] * 2];
        s0 += p.x;
        s1 += p.y;
    }
    float inv = 1.f / fmaxf((float)deg, 1.f);
    float4 me = plr[d];
    out[(size_t)d * 2 + 0] = s0 * inv + me.z + b2[0];
    out[(size_t)d * 2 + 1] = s1 * inv + me.w + b2[1];
}

extern "C" void kernel_launch(void* const* d_in, const int* in_sizes, int n_in,
                              void* d_out, int out_size, void* d_ws, size_t ws_size,
                              hipStream_t stream) {
    const float* x = (const float*)d_in[0];
    const int* ei = (const int*)d_in[1];
    const float* W1l = (const float*)d_in[2];
    const float* W1r = (const float*)d_in[3];
    const float* b1 = (const float*)d_in[4];
    const float* gamma = (const float*)d_in[5];
    const float* beta = (const float*)d_in[6];
    const float* W2l = (const float*)d_in[7];
    const float* W2r = (const float*)d_in[8];
    const float* b2 = (const float*)d_in[9];
    float* out = (float*)d_out;
    float* ws = (float*)d_ws;
    int* wsi = (int*)d_ws;

    const int* src = ei;
    const int* dst = ei + NE;

    int* hist = wsi + OFF_HIST;
    int* offs = wsi + OFF_OFFS;
    int* csr = wsi + OFF_CSR;
    int* bsum = wsi + OFF_PLR;        // scan partials (dead before k_proj)
    int* gcur = wsi + OFF_PLR + 512;  // bucket cursors (dead before k_proj)
    float* bnsum = ws + OFF_BNSUM;
    float* bnsq = ws + OFF_BNSQ;
    float4* plr = (float4*)(ws + OFF_PLR);

    ushort* hb = (ushort*)(ws + OFF_H);
    int2* ebuf = (int2*)(ws + OFF_H);  // overlays hb (dead before hb is written)
    ushort* wfrag = (ushort*)(ws + OFF_WF);
    ushort* aggb16 = (ushort*)(ws + OFF_AGB);
    ushort* xb = (ushort*)(ws + OFF_XB);

    // zero hist + bn partials
    hipMemsetAsync(ws, 0, (size_t)(NN + 256) * sizeof(float), stream);

    k_prep<<<(NE + 255) / 256, 256, 0, stream>>>(dst, x, W1l, W1r, hist, xb, wfrag);
    k_scan1<<<NSCAN, 1024, 0, stream>>>(hist, offs, bsum);
    k_scan3<<<NSCAN, 1024, 0, stream>>>(offs, bsum, gcur);
    k_bucket<<<256, 256, 0, stream>>>(src, dst, gcur, ebuf);
    k_place<<<NB, 1024, 0, stream>>>(ebuf, offs, csr);
    k_aggv<<<(NN * 64 + 255) / 256, 256, 0, stream>>>(xb, offs, csr, aggb16);
    k_mmx<<<782, 256, 0, stream>>>(aggb16, xb, wfrag, b1, hb, bnsum, bnsq);
    k_proj<<<(NN + 3) / 4, 256, 0, stream>>>(hb, bnsum, bnsq, gamma, beta, W2l, W2r, plr);
    k_out<<<(NN + 255) / 256, 256, 0, stream>>>(plr, offs, csr, b2, out);
}

// Round 11
// 227.630 us; speedup vs baseline: 2.3314x; 1.2004x over previous
//
#include <hip/hip_runtime.h>
#include <hip/hip_bf16.h>

#define NN 100000
#define NE 1000000
#define DIN 64
#define DH 128
#define NB 98        // dst-buckets of 1024 nodes
#define CAP 16384    // fixed slots per bucket (max expected ~10.7k)
#define NTILES 1563  // ceil(NN/64)

typedef __attribute__((ext_vector_type(8))) short short8;
typedef __attribute__((ext_vector_type(4))) float floatx4;

// ---- workspace layout (32-bit words) ----
// bnsum[128] | bnsq[128] | gcur[98]+pad | offs[NN+1]+pad | csr[NE] | plr[NN*4] |
// wfrag[8192] | aggb16[NN*32] | xb[NN*32] | hb[NN*64 (bf16)]
// ebuf (int2, NB*CAP pairs = 3.2M words) overlays the hb region (disjoint lifetime).
#define OFF_BN    0
#define OFF_GCUR  256
#define OFF_OFFS  384
#define OFF_CSR   (OFF_OFFS + NN + 4)
#define OFF_PLR   (OFF_CSR + NE)
#define OFF_WF    (OFF_PLR + NN * 4)
#define OFF_AGB   (OFF_WF + 8192)
#define OFF_XB    (OFF_AGB + NN * 32)
#define OFF_H     (OFF_XB + NN * 32)

static __device__ __forceinline__ float b2f(short s) {
    union { unsigned u; float f; } c;
    c.u = ((unsigned)(unsigned short)s) << 16;
    return c.f;
}

// ---------------- prep: x->bf16 + weight fragments + gcur/bn init (no edges!) ----------------
__global__ __launch_bounds__(256) void k_prep(const float* __restrict__ x,
                                              const float* __restrict__ W1l,
                                              const float* __restrict__ W1r,
                                              ushort* __restrict__ xb,
                                              ushort* __restrict__ wfrag,
                                              int* __restrict__ gcur,
                                              float* __restrict__ bnzero) {
    int t = blockIdx.x * 256 + threadIdx.x;
    if (t < NN * DIN / 8) {
        float4 a = *(const float4*)(x + (size_t)t * 8);
        float4 b = *(const float4*)(x + (size_t)t * 8 + 4);
        __hip_bfloat16 o[8];
        o[0] = __float2bfloat16(a.x); o[1] = __float2bfloat16(a.y);
        o[2] = __float2bfloat16(a.z); o[3] = __float2bfloat16(a.w);
        o[4] = __float2bfloat16(b.x); o[5] = __float2bfloat16(b.y);
        o[6] = __float2bfloat16(b.z); o[7] = __float2bfloat16(b.w);
        *(uint4*)&xb[(size_t)t * 8] = *(uint4*)o;
    }
    if (t < 2048) {  // wfrag[((ct*4+ks)*64+l)*8+j] = Wcat[ks*32+(l>>4)*8+j][ct*16+(l&15)]
        int ct = t >> 8, ks = (t >> 6) & 3, l = t & 63;
        int k0 = ks * 32 + (l >> 4) * 8;
        int col = ct * 16 + (l & 15);
        ushort o[8];
#pragma unroll
        for (int j = 0; j < 8; ++j) {
            int k = k0 + j;
            float v = (k < 64) ? W1l[k * DH + col] : W1r[(k - 64) * DH + col];
            __hip_bfloat16 b = __float2bfloat16(v);
            o[j] = *(ushort*)&b;
        }
        *(uint4*)&wfrag[(size_t)t * 8] = *(uint4*)o;
    }
    if (t < NB) gcur[t] = t * CAP;  // bucket append cursors
    if (t < 256) bnzero[t] = 0.f;   // bnsum|bnsq
}

// ---------------- bucket scatter: (src,dst) -> fixed-capacity dst-buckets ----------------
// per-block LDS counts -> contiguous claim on gcur[b] -> full-line writebacks.
__global__ __launch_bounds__(256) void k_bucket(const int* __restrict__ src,
                                                const int* __restrict__ dst,
                                                int* __restrict__ gcur,
                                                int2* __restrict__ ebuf) {
    __shared__ int lh[NB], lb[NB];
    const int tid = threadIdx.x;
    const int per = (NE + gridDim.x - 1) / gridDim.x;
    const int e0 = blockIdx.x * per, e1 = min(e0 + per, NE);
    if (tid < NB) lh[tid] = 0;
    __syncthreads();
    for (int e = e0 + tid; e < e1; e += 256)
        atomicAdd(&lh[dst[e] >> 10], 1);
    __syncthreads();
    if (tid < NB) { lb[tid] = atomicAdd(&gcur[tid], lh[tid]); lh[tid] = 0; }
    __syncthreads();
    for (int e = e0 + tid; e < e1; e += 256) {
        int d = dst[e];
        int b = d >> 10;
        int slot = lb[b] + atomicAdd(&lh[b], 1);
        ebuf[slot] = make_int2(src[e], d);
    }
}

// ---------------- place: per-bucket node-histogram + scan -> offs + csr ----------------
// absorbs the old hist/scan1/scan3 chain; all counting stays in LDS.
__global__ __launch_bounds__(1024) void k_place(const int2* __restrict__ ebuf,
                                                const int* __restrict__ gcur,
                                                int* __restrict__ offs,
                                                int* __restrict__ csr) {
    __shared__ int lcnt[1024], loff[1024];
    __shared__ int sbase;
    const int b = blockIdx.x;
    const int tid = threadIdx.x;
    const int nb0 = b << 10;
    const int node_n = min(1024, NN - nb0);
    lcnt[tid] = 0;
    __syncthreads();
    if (tid == 0) {  // bucket base = prefix of earlier bucket counts (overlaps counting)
        int acc = 0;
        for (int j = 0; j < b; ++j) acc += gcur[j] - j * CAP;
        sbase = acc;
    }
    const int e0 = b * CAP;
    const int ecnt = gcur[b] - e0;
    for (int i = tid; i < ecnt; i += 1024)
        atomicAdd(&lcnt[ebuf[e0 + i].y - nb0], 1);
    __syncthreads();
    // Hillis-Steele scan of lcnt -> exclusive prefix
    int v = lcnt[tid];
    int sum = v;
    loff[tid] = sum;
    __syncthreads();
    for (int off = 1; off < 1024; off <<= 1) {
        int o = (tid >= off) ? loff[tid - off] : 0;
        __syncthreads();
        sum += o;
        loff[tid] = sum;
        __syncthreads();
    }
    const int excl = sum - v;
    const int base = sbase;
    if (tid < node_n) offs[nb0 + tid] = base + excl;
    if (b == NB - 1 && tid == 0) offs[NN] = NE;
    lcnt[tid] = 0;
    loff[tid] = excl;
    __syncthreads();
    for (int i = tid; i < ecnt; i += 1024) {
        int2 e = ebuf[e0 + i];
        int d = e.y - nb0;
        int slot = base + loff[d] + atomicAdd(&lcnt[d], 1);
        csr[slot] = e.x;
    }
}

// ---------------- agg: vectorized CSR gather-mean (16B/lane) ----------------
__global__ __launch_bounds__(256) void k_aggv(const ushort* __restrict__ xb,
                                              const int* __restrict__ offs,
                                              const int* __restrict__ csr,
                                              ushort* __restrict__ aggb16) {
    int wid = (blockIdx.x * 256 + threadIdx.x) >> 6;  // node
    int l = threadIdx.x & 63;
    if (wid >= NN) return;
    int beg = offs[wid];
    int deg = offs[wid + 1] - beg;
    const int g = l >> 3, d8 = l & 7;
    float a[8] = {0, 0, 0, 0, 0, 0, 0, 0};
    for (int ch = 0; ch < deg; ch += 8) {
        int j = ch + g;
        if (j < deg) {
            int sv = csr[beg + j];
            short8 v = *(const short8*)&xb[(size_t)sv * DIN + d8 * 8];
#pragma unroll
            for (int i = 0; i < 8; ++i) a[i] += b2f(v[i]);
        }
    }
#pragma unroll
    for (int i = 0; i < 8; ++i) {
        a[i] += __shfl_xor(a[i], 8);
        a[i] += __shfl_xor(a[i], 16);
        a[i] += __shfl_xor(a[i], 32);
    }
    if (g == 0) {  // lanes 0..7 write 16B each -> 128B contiguous row
        float inv = 1.f / fmaxf((float)deg, 1.f);
        ushort o[8];
#pragma unroll
        for (int i = 0; i < 8; ++i) {
            __hip_bfloat16 b = __float2bfloat16(a[i] * inv);
            o[i] = *(ushort*)&b;
        }
        *(uint4*)&aggb16[(size_t)wid * DIN + d8 * 8] = *(uint4*)o;
    }
}

// ---------------- MFMA dual-GEMM: hb = bf16([agg|x] @ [W1l;W1r] + b1), BN partials ----
// B-frags in registers (wave w owns ct = {2w, 2w+1}); LDS = A-tile only (17 KB).
__global__ __launch_bounds__(256, 4) void k_mmx(const ushort* __restrict__ aggb16,
                                                const ushort* __restrict__ xb,
                                                const ushort* __restrict__ wfrag,
                                                const float* __restrict__ b1,
                                                ushort* __restrict__ hb,
                                                float* __restrict__ bnsum,
                                                float* __restrict__ bnsq) {
    __shared__ ushort sA[64 * 136];  // 17 KB, padded stride 136
    const int tid = threadIdx.x;
    const int l = tid & 63, w = tid >> 6;
    const int r0 = l & 15, kg = l >> 4;

    short8 bf[2][4];
#pragma unroll
    for (int c = 0; c < 2; ++c)
#pragma unroll
        for (int ks = 0; ks < 4; ++ks)
            bf[c][ks] = *(const short8*)&wfrag[(((2 * w + c) * 4 + ks) * 64 + l) * 8];

    float bias2[2];
    bias2[0] = b1[(2 * w) * 16 + r0];
    bias2[1] = b1[(2 * w + 1) * 16 + r0];

    float psum2[2] = {0.f, 0.f}, psq2[2] = {0.f, 0.f};

    for (int tile = blockIdx.x; tile < NTILES; tile += gridDim.x) {
        const int tb = tile * 64;
        __syncthreads();  // prior-iter sA readers done
#pragma unroll
        for (int i = 0; i < 4; ++i) {
            int f = tid + i * 256;  // 0..1023 16B-chunks
            int row = f >> 4, ch = f & 15;
            const uint4* src = (ch < 8)
                ? (const uint4*)(aggb16 + (size_t)(tb + row) * 64 + ch * 8)
                : (const uint4*)(xb + (size_t)(tb + row) * 64 + (ch - 8) * 8);
            *(uint4*)&sA[row * 136 + ch * 8] = *src;
        }
        __syncthreads();

#pragma unroll
        for (int s = 0; s < 4; ++s) {
            short8 af[4];
            const int abase = (s * 16 + r0) * 136 + kg * 8;
#pragma unroll
            for (int ks = 0; ks < 4; ++ks)
                af[ks] = *(const short8*)&sA[abase + ks * 32];
#pragma unroll
            for (int c = 0; c < 2; ++c) {
                floatx4 acc = {0.f, 0.f, 0.f, 0.f};
#pragma unroll
                for (int ks = 0; ks < 4; ++ks)
                    acc = __builtin_amdgcn_mfma_f32_16x16x32_bf16(af[ks], bf[c][ks], acc, 0, 0, 0);
                const int col = (2 * w + c) * 16 + r0;
#pragma unroll
                for (int i = 0; i < 4; ++i) {
                    int r = tb + s * 16 + kg * 4 + i;
                    if (r < NN) {
                        float o = acc[i] + bias2[c];
                        __hip_bfloat16 ob = __float2bfloat16(o);
                        hb[(size_t)r * DH + col] = *(ushort*)&ob;
                        psum2[c] += o;
                        psq2[c] += o * o;
                    }
                }
            }
        }
    }

#pragma unroll
    for (int c = 0; c < 2; ++c) {
        float s = psum2[c], q = psq2[c];
        s += __shfl_xor(s, 16); s += __shfl_xor(s, 32);
        q += __shfl_xor(q, 16); q += __shfl_xor(q, 32);
        if (kg == 0) {  // lanes 0..15, channels disjoint across waves
            atomicAdd(&bnsum[(2 * w + c) * 16 + r0], s);
            atomicAdd(&bnsq[(2 * w + c) * 16 + r0], q);
        }
    }
}

// ---------------- per-node projection (BN affine computed per-block in LDS) ----------------
__global__ __launch_bounds__(256) void k_proj(const ushort* __restrict__ hb,
                                              const float* __restrict__ bnsum,
                                              const float* __restrict__ bnsq,
                                              const float* __restrict__ gamma,
                                              const float* __restrict__ beta,
                                              const float* __restrict__ W2l,
                                              const float* __restrict__ W2r,
                                              float4* __restrict__ plr) {
    __shared__ float sCA[DH], sCC[DH];
    int tid = threadIdx.x;
    if (tid < DH) {
        float mu = bnsum[tid] * (1.f / NN);
        float var = bnsq[tid] * (1.f / NN) - mu * mu;
        float a = rsqrtf(var + 1e-5f) * gamma[tid];
        sCA[tid] = a;
        sCC[tid] = beta[tid] - mu * a;
    }
    __syncthreads();
    int wid = (blockIdx.x * 256 + tid) >> 6;  // node
    int lane = tid & 63;
    if (wid >= NN) return;
    int c0 = lane * 2;
    uint hv = *(const uint*)&hb[(size_t)wid * DH + c0];
    float h0 = b2f((short)(hv & 0xffff));
    float h1 = b2f((short)(hv >> 16));
    float hb0 = fmaxf(h0 * sCA[c0] + sCC[c0], 0.f);
    float hb1 = fmaxf(h1 * sCA[c0 + 1] + sCC[c0 + 1], 0.f);
    float pl0 = hb0 * W2l[c0 * 2 + 0] + hb1 * W2l[c0 * 2 + 2];
    float pl1 = hb0 * W2l[c0 * 2 + 1] + hb1 * W2l[c0 * 2 + 3];
    float pr0 = hb0 * W2r[c0 * 2 + 0] + hb1 * W2r[c0 * 2 + 2];
    float pr1 = hb0 * W2r[c0 * 2 + 1] + hb1 * W2r[c0 * 2 + 3];
#pragma unroll
    for (int off = 32; off > 0; off >>= 1) {
        pl0 += __shfl_down(pl0, off);
        pl1 += __shfl_down(pl1, off);
        pr0 += __shfl_down(pr0, off);
        pr1 += __shfl_down(pr1, off);
    }
    if (lane == 0) plr[wid] = make_float4(pl0, pl1, pr0, pr1);
}

// ---------------- layer-2 aggregate + output (4-way unrolled gather) ----------------
__global__ __launch_bounds__(256) void k_out(const float4* __restrict__ plr,
                                             const int* __restrict__ offs,
                                             const int* __restrict__ csr,
                                             const float* __restrict__ b2,
                                             float* __restrict__ out) {
    int d = blockIdx.x * 256 + threadIdx.x;
    if (d >= NN) return;
    int beg = offs[d];
    int deg = offs[d + 1] - beg;
    const float2* pl2 = (const float2*)plr;
    float s0 = 0.f, s1 = 0.f;
    int i = 0;
    for (; i + 4 <= deg; i += 4) {
        int n0 = csr[beg + i], n1 = csr[beg + i + 1];
        int n2 = csr[beg + i + 2], n3 = csr[beg + i + 3];
        float2 p0 = pl2[(size_t)n0 * 2];
        float2 p1 = pl2[(size_t)n1 * 2];
        float2 p2 = pl2[(size_t)n2 * 2];
        float2 p3 = pl2[(size_t)n3 * 2];
        s0 += (p0.x + p1.x) + (p2.x + p3.x);
        s1 += (p0.y + p1.y) + (p2.y + p3.y);
    }
    for (; i < deg; ++i) {
        float2 p = pl2[(size_t)csr[beg + i] * 2];
        s0 += p.x;
        s1 += p.y;
    }
    float inv = 1.f / fmaxf((float)deg, 1.f);
    float4 me = plr[d];
    out[(size_t)d * 2 + 0] = s0 * inv + me.z + b2[0];
    out[(size_t)d * 2 + 1] = s1 * inv + me.w + b2[1];
}

extern "C" void kernel_launch(void* const* d_in, const int* in_sizes, int n_in,
                              void* d_out, int out_size, void* d_ws, size_t ws_size,
                              hipStream_t stream) {
    const float* x = (const float*)d_in[0];
    const int* ei = (const int*)d_in[1];
    const float* W1l = (const float*)d_in[2];
    const float* W1r = (const float*)d_in[3];
    const float* b1 = (const float*)d_in[4];
    const float* gamma = (const float*)d_in[5];
    const float* beta = (const float*)d_in[6];
    const float* W2l = (const float*)d_in[7];
    const float* W2r = (const float*)d_in[8];
    const float* b2 = (const float*)d_in[9];
    float* out = (float*)d_out;
    float* ws = (float*)d_ws;
    int* wsi = (int*)d_ws;

    const int* src = ei;
    const int* dst = ei + NE;

    float* bnsum = ws + OFF_BN;
    float* bnsq = ws + OFF_BN + 128;
    int* gcur = wsi + OFF_GCUR;
    int* offs = wsi + OFF_OFFS;
    int* csr = wsi + OFF_CSR;
    float4* plr = (float4*)(ws + OFF_PLR);
    ushort* wfrag = (ushort*)(ws + OFF_WF);
    ushort* aggb16 = (ushort*)(ws + OFF_AGB);
    ushort* xb = (ushort*)(ws + OFF_XB);
    ushort* hb = (ushort*)(ws + OFF_H);
    int2* ebuf = (int2*)(ws + OFF_H);  // overlays hb (dead before hb is written)

    k_prep<<<(NN * DIN / 8 + 255) / 256, 256, 0, stream>>>(x, W1l, W1r, xb, wfrag, gcur, ws + OFF_BN);
    k_bucket<<<256, 256, 0, stream>>>(src, dst, gcur, ebuf);
    k_place<<<NB, 1024, 0, stream>>>(ebuf, gcur, offs, csr);
    k_aggv<<<(NN * 64 + 255) / 256, 256, 0, stream>>>(xb, offs, csr, aggb16);
    k_mmx<<<782, 256, 0, stream>>>(aggb16, xb, wfrag, b1, hb, bnsum, bnsq);
    k_proj<<<(NN + 3) / 4, 256, 0, stream>>>(hb, bnsum, bnsq, gamma, beta, W2l, W2r, plr);
    k_out<<<(NN + 255) / 256, 256, 0, stream>>>(plr, offs, csr, b2, out);
}

// Round 12
// 224.920 us; speedup vs baseline: 2.3595x; 1.0121x over previous
//
#include <hip/hip_runtime.h>
#include <hip/hip_bf16.h>

#define NN 100000
#define NE 1000000
#define DIN 64
#define DH 128
#define NB 98        // dst-buckets of 1024 nodes
#define CAP 16384    // fixed slots per bucket (max expected ~10.7k)
#define NTILES 1563  // ceil(NN/64)
#define EDGEB 256    // blocks doing edge-bucket role
#define CVTB 3125    // blocks doing convert role (NN*DIN/8 / 256)

typedef __attribute__((ext_vector_type(8))) short short8;
typedef __attribute__((ext_vector_type(4))) float floatx4;

// ---- workspace layout (32-bit words) ----
// bnsum[128]|bnsq[128] | gcur[98]+pad | offs[NN+1]+pad | csr[NE] | plr[NN*4] |
// wfrag[8192] | aggb16[NN*32] | xb[NN*32] | hb[NN*64 bf16]
// ebuf (packed int, NB*CAP = 1.6M words) overlays the hb region (disjoint lifetime).
#define OFF_BN    0
#define OFF_GCUR  256
#define OFF_OFFS  384
#define OFF_CSR   (OFF_OFFS + NN + 4)
#define OFF_PLR   (OFF_CSR + NE)
#define OFF_WF    (OFF_PLR + NN * 4)
#define OFF_AGB   (OFF_WF + 8192)
#define OFF_XB    (OFF_AGB + NN * 32)
#define OFF_H     (OFF_XB + NN * 32)

static __device__ __forceinline__ float b2f(short s) {
    union { unsigned u; float f; } c;
    c.u = ((unsigned)(unsigned short)s) << 16;
    return c.f;
}

// ------- fused: edge bucketing (blocks 0..255) + x->bf16 / wfrag (blocks 256+) -------
__global__ __launch_bounds__(256) void k_bucketprep(const float* __restrict__ x,
                                                    const float* __restrict__ W1l,
                                                    const float* __restrict__ W1r,
                                                    const int* __restrict__ src,
                                                    const int* __restrict__ dst,
                                                    ushort* __restrict__ xb,
                                                    ushort* __restrict__ wfrag,
                                                    int* __restrict__ gcur,
                                                    int* __restrict__ ebuf) {
    const int bid = blockIdx.x;
    const int tid = threadIdx.x;
    if (bid < EDGEB) {
        // edge role: per-block LDS counts -> contiguous claim on gcur[b] -> packed scatter
        __shared__ int lh[NB], lb[NB];
        const int per = (NE + EDGEB - 1) / EDGEB;
        const int e0 = bid * per, e1 = min(e0 + per, NE);
        if (tid < NB) lh[tid] = 0;
        __syncthreads();
        for (int e = e0 + tid; e < e1; e += 256)
            atomicAdd(&lh[dst[e] >> 10], 1);
        __syncthreads();
        if (tid < NB) { lb[tid] = atomicAdd(&gcur[tid], lh[tid]); lh[tid] = 0; }
        __syncthreads();
        for (int e = e0 + tid; e < e1; e += 256) {
            int d = dst[e];
            int b = d >> 10;
            int slot = b * CAP + lb[b] + atomicAdd(&lh[b], 1);
            ebuf[slot] = (src[e] << 10) | (d & 1023);  // pack: src(17b) | dstLocal(10b)
        }
    } else {
        int t = (bid - EDGEB) * 256 + tid;
        if (t < NN * DIN / 8) {
            float4 a = *(const float4*)(x + (size_t)t * 8);
            float4 b = *(const float4*)(x + (size_t)t * 8 + 4);
            __hip_bfloat16 o[8];
            o[0] = __float2bfloat16(a.x); o[1] = __float2bfloat16(a.y);
            o[2] = __float2bfloat16(a.z); o[3] = __float2bfloat16(a.w);
            o[4] = __float2bfloat16(b.x); o[5] = __float2bfloat16(b.y);
            o[6] = __float2bfloat16(b.z); o[7] = __float2bfloat16(b.w);
            *(uint4*)&xb[(size_t)t * 8] = *(uint4*)o;
        }
        if (t < 2048) {  // wfrag[((ct*4+ks)*64+l)*8+j] = Wcat[ks*32+(l>>4)*8+j][ct*16+(l&15)]
            int ct = t >> 8, ks = (t >> 6) & 3, l = t & 63;
            int k0 = ks * 32 + (l >> 4) * 8;
            int col = ct * 16 + (l & 15);
            ushort o[8];
#pragma unroll
            for (int j = 0; j < 8; ++j) {
                int k = k0 + j;
                float v = (k < 64) ? W1l[k * DH + col] : W1r[(k - 64) * DH + col];
                __hip_bfloat16 b = __float2bfloat16(v);
                o[j] = *(ushort*)&b;
            }
            *(uint4*)&wfrag[(size_t)t * 8] = *(uint4*)o;
        }
    }
}

// ------- place: per-bucket node-histogram + scan -> offs + csr (parallel base) -------
__global__ __launch_bounds__(1024) void k_place(const int* __restrict__ ebuf,
                                                const int* __restrict__ gcur,
                                                int* __restrict__ offs,
                                                int* __restrict__ csr) {
    __shared__ int lcnt[1024], loff[1024], pre[NB];
    __shared__ int sbase;
    const int b = blockIdx.x;
    const int tid = threadIdx.x;
    const int nb0 = b << 10;
    const int node_n = min(1024, NN - nb0);
    if (tid < NB) pre[tid] = gcur[tid];  // parallel load of all bucket counts
    lcnt[tid] = 0;
    __syncthreads();
    if (tid == 0) {  // in-LDS prefix (98 adds)
        int acc = 0;
        for (int j = 0; j < b; ++j) acc += pre[j];
        sbase = acc;
    }
    const int e0 = b * CAP;
    const int ecnt = pre[b];
    for (int i = tid; i < ecnt; i += 1024)
        atomicAdd(&lcnt[ebuf[e0 + i] & 1023], 1);
    __syncthreads();
    // Hillis-Steele scan of lcnt -> exclusive prefix
    int v = lcnt[tid];
    int sum = v;
    loff[tid] = sum;
    __syncthreads();
    for (int off = 1; off < 1024; off <<= 1) {
        int o = (tid >= off) ? loff[tid - off] : 0;
        __syncthreads();
        sum += o;
        loff[tid] = sum;
        __syncthreads();
    }
    const int excl = sum - v;
    const int base = sbase;
    if (tid < node_n) offs[nb0 + tid] = base + excl;
    if (b == NB - 1 && tid == 0) offs[NN] = NE;
    lcnt[tid] = 0;
    loff[tid] = excl;
    __syncthreads();
    for (int i = tid; i < ecnt; i += 1024) {
        int e = ebuf[e0 + i];
        int d = e & 1023;
        int slot = base + loff[d] + atomicAdd(&lcnt[d], 1);
        csr[slot] = e >> 10;
    }
}

// ---------------- agg: vectorized CSR gather-mean (16B/lane) ----------------
__global__ __launch_bounds__(256) void k_aggv(const ushort* __restrict__ xb,
                                              const int* __restrict__ offs,
                                              const int* __restrict__ csr,
                                              ushort* __restrict__ aggb16) {
    int wid = (blockIdx.x * 256 + threadIdx.x) >> 6;  // node
    int l = threadIdx.x & 63;
    if (wid >= NN) return;
    int beg = offs[wid];
    int deg = offs[wid + 1] - beg;
    const int g = l >> 3, d8 = l & 7;
    float a[8] = {0, 0, 0, 0, 0, 0, 0, 0};
    for (int ch = 0; ch < deg; ch += 8) {
        int j = ch + g;
        if (j < deg) {
            int sv = csr[beg + j];
            short8 v = *(const short8*)&xb[(size_t)sv * DIN + d8 * 8];
#pragma unroll
            for (int i = 0; i < 8; ++i) a[i] += b2f(v[i]);
        }
    }
#pragma unroll
    for (int i = 0; i < 8; ++i) {
        a[i] += __shfl_xor(a[i], 8);
        a[i] += __shfl_xor(a[i], 16);
        a[i] += __shfl_xor(a[i], 32);
    }
    if (g == 0) {  // lanes 0..7 write 16B each -> 128B contiguous row
        float inv = 1.f / fmaxf((float)deg, 1.f);
        ushort o[8];
#pragma unroll
        for (int i = 0; i < 8; ++i) {
            __hip_bfloat16 b = __float2bfloat16(a[i] * inv);
            o[i] = *(ushort*)&b;
        }
        *(uint4*)&aggb16[(size_t)wid * DIN + d8 * 8] = *(uint4*)o;
    }
}

// ---------------- MFMA dual-GEMM: hb = bf16([agg|x] @ [W1l;W1r] + b1), BN partials ----
__global__ __launch_bounds__(256, 4) void k_mmx(const ushort* __restrict__ aggb16,
                                                const ushort* __restrict__ xb,
                                                const ushort* __restrict__ wfrag,
                                                const float* __restrict__ b1,
                                                ushort* __restrict__ hb,
                                                float* __restrict__ bnsum,
                                                float* __restrict__ bnsq) {
    __shared__ ushort sA[64 * 136];  // 17 KB, padded stride 136
    const int tid = threadIdx.x;
    const int l = tid & 63, w = tid >> 6;
    const int r0 = l & 15, kg = l >> 4;

    short8 bf[2][4];
#pragma unroll
    for (int c = 0; c < 2; ++c)
#pragma unroll
        for (int ks = 0; ks < 4; ++ks)
            bf[c][ks] = *(const short8*)&wfrag[(((2 * w + c) * 4 + ks) * 64 + l) * 8];

    float bias2[2];
    bias2[0] = b1[(2 * w) * 16 + r0];
    bias2[1] = b1[(2 * w + 1) * 16 + r0];

    float psum2[2] = {0.f, 0.f}, psq2[2] = {0.f, 0.f};

    for (int tile = blockIdx.x; tile < NTILES; tile += gridDim.x) {
        const int tb = tile * 64;
        __syncthreads();  // prior-iter sA readers done
#pragma unroll
        for (int i = 0; i < 4; ++i) {
            int f = tid + i * 256;  // 0..1023 16B-chunks
            int row = f >> 4, ch = f & 15;
            const uint4* src = (ch < 8)
                ? (const uint4*)(aggb16 + (size_t)(tb + row) * 64 + ch * 8)
                : (const uint4*)(xb + (size_t)(tb + row) * 64 + (ch - 8) * 8);
            *(uint4*)&sA[row * 136 + ch * 8] = *src;
        }
        __syncthreads();

#pragma unroll
        for (int s = 0; s < 4; ++s) {
            short8 af[4];
            const int abase = (s * 16 + r0) * 136 + kg * 8;
#pragma unroll
            for (int ks = 0; ks < 4; ++ks)
                af[ks] = *(const short8*)&sA[abase + ks * 32];
#pragma unroll
            for (int c = 0; c < 2; ++c) {
                floatx4 acc = {0.f, 0.f, 0.f, 0.f};
#pragma unroll
                for (int ks = 0; ks < 4; ++ks)
                    acc = __builtin_amdgcn_mfma_f32_16x16x32_bf16(af[ks], bf[c][ks], acc, 0, 0, 0);
                const int col = (2 * w + c) * 16 + r0;
#pragma unroll
                for (int i = 0; i < 4; ++i) {
                    int r = tb + s * 16 + kg * 4 + i;
                    if (r < NN) {
                        float o = acc[i] + bias2[c];
                        __hip_bfloat16 ob = __float2bfloat16(o);
                        hb[(size_t)r * DH + col] = *(ushort*)&ob;
                        psum2[c] += o;
                        psq2[c] += o * o;
                    }
                }
            }
        }
    }

#pragma unroll
    for (int c = 0; c < 2; ++c) {
        float s = psum2[c], q = psq2[c];
        s += __shfl_xor(s, 16); s += __shfl_xor(s, 32);
        q += __shfl_xor(q, 16); q += __shfl_xor(q, 32);
        if (kg == 0) {  // lanes 0..15, channels disjoint across waves
            atomicAdd(&bnsum[(2 * w + c) * 16 + r0], s);
            atomicAdd(&bnsq[(2 * w + c) * 16 + r0], q);
        }
    }
}

// ---------------- per-node projection (BN affine computed per-block in LDS) ----------------
__global__ __launch_bounds__(256) void k_proj(const ushort* __restrict__ hb,
                                              const float* __restrict__ bnsum,
                                              const float* __restrict__ bnsq,
                                              const float* __restrict__ gamma,
                                              const float* __restrict__ beta,
                                              const float* __restrict__ W2l,
                                              const float* __restrict__ W2r,
                                              float4* __restrict__ plr) {
    __shared__ float sCA[DH], sCC[DH];
    int tid = threadIdx.x;
    if (tid < DH) {
        float mu = bnsum[tid] * (1.f / NN);
        float var = bnsq[tid] * (1.f / NN) - mu * mu;
        float a = rsqrtf(var + 1e-5f) * gamma[tid];
        sCA[tid] = a;
        sCC[tid] = beta[tid] - mu * a;
    }
    __syncthreads();
    int wid = (blockIdx.x * 256 + tid) >> 6;  // node
    int lane = tid & 63;
    if (wid >= NN) return;
    int c0 = lane * 2;
    uint hv = *(const uint*)&hb[(size_t)wid * DH + c0];
    float h0 = b2f((short)(hv & 0xffff));
    float h1 = b2f((short)(hv >> 16));
    float hb0 = fmaxf(h0 * sCA[c0] + sCC[c0], 0.f);
    float hb1 = fmaxf(h1 * sCA[c0 + 1] + sCC[c0 + 1], 0.f);
    float pl0 = hb0 * W2l[c0 * 2 + 0] + hb1 * W2l[c0 * 2 + 2];
    float pl1 = hb0 * W2l[c0 * 2 + 1] + hb1 * W2l[c0 * 2 + 3];
    float pr0 = hb0 * W2r[c0 * 2 + 0] + hb1 * W2r[c0 * 2 + 2];
    float pr1 = hb0 * W2r[c0 * 2 + 1] + hb1 * W2r[c0 * 2 + 3];
#pragma unroll
    for (int off = 32; off > 0; off >>= 1) {
        pl0 += __shfl_down(pl0, off);
        pl1 += __shfl_down(pl1, off);
        pr0 += __shfl_down(pr0, off);
        pr1 += __shfl_down(pr1, off);
    }
    if (lane == 0) plr[wid] = make_float4(pl0, pl1, pr0, pr1);
}

// ---------------- layer-2 aggregate + output (4-way unrolled gather) ----------------
__global__ __launch_bounds__(256) void k_out(const float4* __restrict__ plr,
                                             const int* __restrict__ offs,
                                             const int* __restrict__ csr,
                                             const float* __restrict__ b2,
                                             float* __restrict__ out) {
    int d = blockIdx.x * 256 + threadIdx.x;
    if (d >= NN) return;
    int beg = offs[d];
    int deg = offs[d + 1] - beg;
    const float2* pl2 = (const float2*)plr;
    float s0 = 0.f, s1 = 0.f;
    int i = 0;
    for (; i + 4 <= deg; i += 4) {
        int n0 = csr[beg + i], n1 = csr[beg + i + 1];
        int n2 = csr[beg + i + 2], n3 = csr[beg + i + 3];
        float2 p0 = pl2[(size_t)n0 * 2];
        float2 p1 = pl2[(size_t)n1 * 2];
        float2 p2 = pl2[(size_t)n2 * 2];
        float2 p3 = pl2[(size_t)n3 * 2];
        s0 += (p0.x + p1.x) + (p2.x + p3.x);
        s1 += (p0.y + p1.y) + (p2.y + p3.y);
    }
    for (; i < deg; ++i) {
        float2 p = pl2[(size_t)csr[beg + i] * 2];
        s0 += p.x;
        s1 += p.y;
    }
    float inv = 1.f / fmaxf((float)deg, 1.f);
    float4 me = plr[d];
    out[(size_t)d * 2 + 0] = s0 * inv + me.z + b2[0];
    out[(size_t)d * 2 + 1] = s1 * inv + me.w + b2[1];
}

extern "C" void kernel_launch(void* const* d_in, const int* in_sizes, int n_in,
                              void* d_out, int out_size, void* d_ws, size_t ws_size,
                              hipStream_t stream) {
    const float* x = (const float*)d_in[0];
    const int* ei = (const int*)d_in[1];
    const float* W1l = (const float*)d_in[2];
    const float* W1r = (const float*)d_in[3];
    const float* b1 = (const float*)d_in[4];
    const float* gamma = (const float*)d_in[5];
    const float* beta = (const float*)d_in[6];
    const float* W2l = (const float*)d_in[7];
    const float* W2r = (const float*)d_in[8];
    const float* b2 = (const float*)d_in[9];
    float* out = (float*)d_out;
    float* ws = (float*)d_ws;
    int* wsi = (int*)d_ws;

    const int* src = ei;
    const int* dst = ei + NE;

    float* bnsum = ws + OFF_BN;
    float* bnsq = ws + OFF_BN + 128;
    int* gcur = wsi + OFF_GCUR;
    int* offs = wsi + OFF_OFFS;
    int* csr = wsi + OFF_CSR;
    float4* plr = (float4*)(ws + OFF_PLR);
    ushort* wfrag = (ushort*)(ws + OFF_WF);
    ushort* aggb16 = (ushort*)(ws + OFF_AGB);
    ushort* xb = (ushort*)(ws + OFF_XB);
    ushort* hb = (ushort*)(ws + OFF_H);
    int* ebuf = (int*)(ws + OFF_H);  // overlays hb (dead before hb is written)

    // zero bn partials (256) + gcur (98) in one small memset (adjacent in layout)
    hipMemsetAsync(ws, 0, (256 + NB) * sizeof(float), stream);

    k_bucketprep<<<EDGEB + CVTB, 256, 0, stream>>>(x, W1l, W1r, src, dst, xb, wfrag, gcur, ebuf);
    k_place<<<NB, 1024, 0, stream>>>(ebuf, gcur, offs, csr);
    k_aggv<<<(NN * 64 + 255) / 256, 256, 0, stream>>>(xb, offs, csr, aggb16);
    k_mmx<<<782, 256, 0, stream>>>(aggb16, xb, wfrag, b1, hb, bnsum, bnsq);
    k_proj<<<(NN + 3) / 4, 256, 0, stream>>>(hb, bnsum, bnsq, gamma, beta, W2l, W2r, plr);
    k_out<<<(NN + 255) / 256, 256, 0, stream>>>(plr, offs, csr, b2, out);
}